// Round 1
// baseline (476.901 us; speedup 1.0000x reference)
//
#include <hip/hip_runtime.h>
#include <hip/hip_bf16.h>

#define GAS __attribute__((address_space(1)))
#define LAS __attribute__((address_space(3)))

typedef __attribute__((ext_vector_type(8))) short   bf16x8;
typedef __attribute__((ext_vector_type(4))) float   f32x4;
typedef __attribute__((ext_vector_type(4))) float   f4;
typedef __attribute__((ext_vector_type(8))) short   s8v;
typedef __attribute__((ext_vector_type(2))) unsigned int u32x2;

#define NB  64
#define NS  512
#define ND  768
#define NH  12
#define NHS 64
#define NM  (NB*NS)    /* 32768 */
#define NBH (NB*NH)    /* 768   */

__device__ __forceinline__ unsigned short f2bf(float x){
  unsigned int u = __float_as_uint(x);
  u += 0x7fffu + ((u >> 16) & 1u);       // round-to-nearest-even
  return (unsigned short)(u >> 16);
}

__device__ __forceinline__ f32x4 mfma16(bf16x8 a, bf16x8 b, f32x4 c){
  return __builtin_amdgcn_mfma_f32_16x16x32_bf16(a, b, c, 0, 0, 0);
}

// ---------------- fp32 -> bf16 convert of activations ----------------
__global__ void cvt_x(const float* __restrict__ from_t, const float* __restrict__ to_t,
                      short* __restrict__ fb, short* __restrict__ tb){
  int v = blockIdx.x * 256 + threadIdx.x;          // one thread = 8 elems
  const int NG = NM * ND / 8;                      // 3145728 per tensor
  const float* s; short* d;
  if (v < NG){ s = from_t; d = fb; } else { s = to_t; d = tb; v -= NG; }
  f4 a = ((const f4*)s)[(long)v * 2];
  f4 b = ((const f4*)s)[(long)v * 2 + 1];
  s8v o;
  o[0]=(short)f2bf(a[0]); o[1]=(short)f2bf(a[1]); o[2]=(short)f2bf(a[2]); o[3]=(short)f2bf(a[3]);
  o[4]=(short)f2bf(b[0]); o[5]=(short)f2bf(b[1]); o[6]=(short)f2bf(b[2]); o[7]=(short)f2bf(b[3]);
  ((s8v*)d)[v] = o;
}

// ---------------- W [k][n] fp32 -> Wt [mat][n][k] bf16 ----------------
__global__ void cvt_w(const float* __restrict__ Wq, const float* __restrict__ Wk,
                      const float* __restrict__ Wv, short* __restrict__ Wt){
  int i = blockIdx.x * 256 + threadIdx.x;          // 0 .. 3*768*768-1
  int mat = i / (ND*ND);
  int rem = i - mat * (ND*ND);
  int k = rem / ND;
  int n = rem - k * ND;
  const float* W = (mat == 0) ? Wq : (mat == 1 ? Wk : Wv);
  Wt[(long)mat*ND*ND + (long)n*ND + k] = (short)f2bf(W[rem]);
}

// ---------------- fused QKV GEMM: [32768,768] x [768,768] + bias ----------------
// A (activations) bf16 row-major; Wt bf16 [n][k]; out Q/K as [b,h,s,hs] bf16,
// V as [b,h,hs,s] bf16 (pre-transposed for attention PV).
__global__ __launch_bounds__(256, 2)
void qkv_gemm(const short* __restrict__ Xf, const short* __restrict__ Xt,
              const short* __restrict__ Wt,
              const float* __restrict__ bq, const float* __restrict__ bk,
              const float* __restrict__ bv,
              short* __restrict__ Qw, short* __restrict__ Kw, short* __restrict__ Vtw){
  __shared__ short As[2][128*64];   // 16 KB each buf
  __shared__ short Bs[2][128*64];

  int bid = blockIdx.x;                       // 4608 blocks, 4608%8==0
  int wg  = (bid & 7) * 576 + (bid >> 3);     // XCD-contiguous chunks
  int mat = wg / 1536;
  int r   = wg - mat * 1536;
  int mt  = r / 6;
  int nt  = r - mt * 6;

  const short* A  = (mat == 0) ? Xf : Xt;
  const short* W  = Wt + (long)mat * ND * ND;
  const float* bias = (mat == 0) ? bq : (mat == 1 ? bk : bv);

  int t = threadIdx.x, wv = t >> 6, l = t & 63, g = l >> 4, c = l & 15;
  int wm = wv >> 1, wn = wv & 1;
  int m0 = mt * 128, n0 = nt * 128;

  auto stage = [&](int buf, int kt){
    #pragma unroll
    for (int it = 0; it < 4; ++it){
      int chunk = it * 4 + wv;                 // wave-uniform
      int idx = chunk * 64 + l;
      int row = idx >> 3, slot = idx & 7;      // 128 rows x 8 slots of 16B
      // linear LDS dest + inverse-swizzled global source (rule #21)
      const short* ga = A + (long)(m0 + row) * ND + kt * 64 + ((slot ^ (row & 7)) * 8);
      __builtin_amdgcn_global_load_lds((const GAS unsigned int*)ga,
                                       (LAS unsigned int*)(&As[buf][chunk * 512]), 16, 0, 0);
      const short* gb = W + (long)(n0 + row) * ND + kt * 64 + ((slot ^ (row & 7)) * 8);
      __builtin_amdgcn_global_load_lds((const GAS unsigned int*)gb,
                                       (LAS unsigned int*)(&Bs[buf][chunk * 512]), 16, 0, 0);
    }
  };

  f32x4 zero = {0.f, 0.f, 0.f, 0.f};
  f32x4 acc[4][4];
  #pragma unroll
  for (int i = 0; i < 4; ++i)
    #pragma unroll
    for (int j = 0; j < 4; ++j) acc[i][j] = zero;

  stage(0, 0);
  __syncthreads();
  int buf = 0;
  for (int kt = 0; kt < 12; ++kt){
    if (kt < 11) stage(buf ^ 1, kt + 1);
    #pragma unroll
    for (int kk = 0; kk < 2; ++kk){
      bf16x8 af[4], bfv[4];
      #pragma unroll
      for (int ms = 0; ms < 4; ++ms){
        int row = wm * 64 + ms * 16 + c;
        af[ms] = *(const bf16x8*)((const char*)&As[buf][0] + row * 128 +
                                  (((kk * 4 + g) ^ (row & 7)) << 4));
      }
      #pragma unroll
      for (int ns = 0; ns < 4; ++ns){
        int row = wn * 64 + ns * 16 + c;
        bfv[ns] = *(const bf16x8*)((const char*)&Bs[buf][0] + row * 128 +
                                   (((kk * 4 + g) ^ (row & 7)) << 4));
      }
      #pragma unroll
      for (int ms = 0; ms < 4; ++ms)
        #pragma unroll
        for (int ns = 0; ns < 4; ++ns)
          acc[ms][ns] = mfma16(af[ms], bfv[ns], acc[ms][ns]);
    }
    __syncthreads();
    buf ^= 1;
  }

  // Epilogue: C row = wm*64+ms*16+g*4+i (an s index), col = wn*64+ns*16+c (h,hs)
  if (mat < 2){
    short* O = (mat == 0) ? Qw : Kw;
    #pragma unroll
    for (int ms = 0; ms < 4; ++ms){
      #pragma unroll
      for (int ns = 0; ns < 4; ++ns){
        int n = n0 + wn * 64 + ns * 16 + c;
        int h = n >> 6, hs = n & 63;
        float bb = bias[n];
        #pragma unroll
        for (int i = 0; i < 4; ++i){
          int m = m0 + wm * 64 + ms * 16 + g * 4 + i;
          int b = m >> 9, s = m & 511;
          O[(((long)(b * NH + h) * NS + s) << 6) + hs] = (short)f2bf(acc[ms][ns][i] + bb);
        }
      }
    }
  } else {
    #pragma unroll
    for (int ms = 0; ms < 4; ++ms){
      #pragma unroll
      for (int ns = 0; ns < 4; ++ns){
        int n = n0 + wn * 64 + ns * 16 + c;
        int h = n >> 6, hs = n & 63;
        float bb = bias[n];
        int m = m0 + wm * 64 + ms * 16 + g * 4;   // 4 consecutive s per lane
        int b = m >> 9, s = m & 511;
        unsigned int p0 = (unsigned int)f2bf(acc[ms][ns][0]  + bb) |
                          ((unsigned int)f2bf(acc[ms][ns][1] + bb) << 16);
        unsigned int p1 = (unsigned int)f2bf(acc[ms][ns][2]  + bb) |
                          ((unsigned int)f2bf(acc[ms][ns][3] + bb) << 16);
        u32x2 pk; pk[0] = p0; pk[1] = p1;
        short* dst = Vtw + ((long)(b * NH + h) * 64 + hs) * NS + s;
        *(u32x2*)dst = pk;                        // 8B store, s%4==0 -> aligned
      }
    }
  }
}

// ---------------- attention: one (b,h,qtile64) per block, 4 waves x 16 q-rows ----------------
__global__ __launch_bounds__(256, 1)
void attn_kernel(const short* __restrict__ Qw, const short* __restrict__ Kw,
                 const short* __restrict__ Vtw, float* __restrict__ out){
  extern __shared__ char smem[];
  short* Ks = (short*)smem;              // [512][64] bf16, swizzled, 64 KB
  short* Vs = (short*)(smem + 65536);    // [64][512] bf16, swizzled, 64 KB
  short* Ps = (short*)(smem + 131072);   // 4 waves x [16][128] bf16, 16 KB

  int bid = blockIdx.x;                  // 6144 = 8*768
  int wg  = (bid & 7) * 768 + (bid >> 3);// all 8 qtiles of a bh on one XCD
  int bh  = wg >> 3;
  int qt  = wg & 7;

  int t = threadIdx.x, wv = t >> 6, l = t & 63, g = l >> 4, c = l & 15;

  const short* Kb = Kw  + (long)bh * NS * NHS;
  const short* Vb = Vtw + (long)bh * NS * NHS;

  // stage K [key][d] (rows 128B, 8 slots) and Vt [d][key] (rows 1KB, 64 slots)
  #pragma unroll
  for (int it = 0; it < 16; ++it){
    int chunk = it * 4 + wv;             // wave-uniform, 0..63 (1 KB each)
    {
      int idx = chunk * 64 + l;
      int row = idx >> 3, slot = idx & 7;
      const short* gk = Kb + row * 64 + ((slot ^ (row & 7)) * 8);
      __builtin_amdgcn_global_load_lds((const GAS unsigned int*)gk,
                                       (LAS unsigned int*)(Ks + chunk * 512), 16, 0, 0);
    }
    {
      int row = chunk, slot = l;         // one chunk = one d-row
      const short* gv = Vb + (long)row * NS + (((slot & 56) | ((slot & 7) ^ (row & 7))) * 8);
      __builtin_amdgcn_global_load_lds((const GAS unsigned int*)gv,
                                       (LAS unsigned int*)(Vs + chunk * 512), 16, 0, 0);
    }
  }

  // Q fragments straight from global (line-coalesced)
  int q0 = qt * 64 + wv * 16;
  const short* Qb = Qw + ((long)bh * NS + q0 + c) * 64;
  bf16x8 aq0 = *(const bf16x8*)(Qb + g * 8);
  bf16x8 aq1 = *(const bf16x8*)(Qb + 32 + g * 8);

  __syncthreads();

  // ---- scores: full 512-key row in regs. sc[j][i] = S[q=g*4+i][key=j*16+c]
  f32x4 zero = {0.f, 0.f, 0.f, 0.f};
  f32x4 sc[32];
  #pragma unroll
  for (int j = 0; j < 32; ++j) sc[j] = zero;

  #pragma unroll
  for (int j = 0; j < 32; ++j){
    int key = j * 16 + c;
    const char* base = (const char*)Ks + key * 128;
    bf16x8 b0 = *(const bf16x8*)(base + (((0 + g) ^ (key & 7)) << 4));
    bf16x8 b1 = *(const bf16x8*)(base + (((4 + g) ^ (key & 7)) << 4));
    sc[j] = mfma16(aq0, b0, sc[j]);
    sc[j] = mfma16(aq1, b1, sc[j]);
  }

  // ---- softmax: rows live in 16-lane groups; all 64 lanes busy
  #pragma unroll
  for (int i = 0; i < 4; ++i){
    float m = sc[0][i];
    #pragma unroll
    for (int j = 1; j < 32; ++j) m = fmaxf(m, sc[j][i]);
    m = fmaxf(m, __shfl_xor(m, 1));
    m = fmaxf(m, __shfl_xor(m, 2));
    m = fmaxf(m, __shfl_xor(m, 4));
    m = fmaxf(m, __shfl_xor(m, 8));
    float s_ = 0.f;
    #pragma unroll
    for (int j = 0; j < 32; ++j){
      float p = __expf((sc[j][i] - m) * 0.125f);   // scale = 1/sqrt(64)
      sc[j][i] = p;
      s_ += p;
    }
    s_ += __shfl_xor(s_, 1);
    s_ += __shfl_xor(s_, 2);
    s_ += __shfl_xor(s_, 4);
    s_ += __shfl_xor(s_, 8);
    float inv = 1.f / s_;
    #pragma unroll
    for (int j = 0; j < 32; ++j) sc[j][i] *= inv;
  }

  // ---- PV: per-wave-private P chunks through LDS (no barriers needed)
  short* Pw = Ps + wv * 2048;            // [16][128] bf16, rows 256B / 16 slots
  f32x4 o[4];
  #pragma unroll
  for (int ns = 0; ns < 4; ++ns) o[ns] = zero;

  #pragma unroll
  for (int ch = 0; ch < 4; ++ch){
    #pragma unroll
    for (int jl = 0; jl < 8; ++jl){
      int j = ch * 8 + jl;
      #pragma unroll
      for (int i = 0; i < 4; ++i){
        int q = g * 4 + i;
        int kl = jl * 16 + c;
        int slot = kl >> 3;
        int byte = q * 256 + (((slot & 8) | ((slot & 7) ^ (q & 7))) << 4) + ((kl & 7) << 1);
        *(short*)((char*)Pw + byte) = (short)f2bf(sc[j][i]);
      }
    }
    #pragma unroll
    for (int kk = 0; kk < 4; ++kk){
      int slotp = kk * 4 + g;
      bf16x8 ap = *(const bf16x8*)((const char*)Pw + c * 256 +
                                   (((slotp & 8) | ((slotp & 7) ^ (c & 7))) << 4));
      #pragma unroll
      for (int ns = 0; ns < 4; ++ns){
        int d = ns * 16 + c;
        int slotv = ch * 16 + kk * 4 + g;
        bf16x8 bv8 = *(const bf16x8*)((const char*)Vs + d * 1024 +
                                      (((slotv & 56) | ((slotv & 7) ^ (d & 7))) << 4));
        o[ns] = mfma16(ap, bv8, o[ns]);
      }
    }
  }

  // ---- write fp32 output [b,s,h*64+d]
  int b = bh / NH, h = bh - b * NH;
  float* Ob = out + (long)b * NS * ND + (long)h * 64;
  #pragma unroll
  for (int ns = 0; ns < 4; ++ns)
    #pragma unroll
    for (int i = 0; i < 4; ++i){
      int q = q0 + g * 4 + i;
      Ob[(long)q * ND + ns * 16 + c] = o[ns][i];
    }
}

// ---------------- launch ----------------
extern "C" void kernel_launch(void* const* d_in, const int* in_sizes, int n_in,
                              void* d_out, int out_size, void* d_ws, size_t ws_size,
                              hipStream_t stream){
  const float* from_t = (const float*)d_in[0];
  const float* to_t   = (const float*)d_in[1];
  const float* Wq = (const float*)d_in[2];
  const float* bq = (const float*)d_in[3];
  const float* Wk = (const float*)d_in[4];
  const float* bk = (const float*)d_in[5];
  const float* Wv = (const float*)d_in[6];
  const float* bv = (const float*)d_in[7];

  short* fb  = (short*)d_ws;                 // 25165824 bf16
  short* tb  = fb  + 25165824;               // 25165824
  short* Wt  = tb  + 25165824;               // 1769472
  short* Qw  = Wt  + 1769472;                // 25165824
  short* Kw  = Qw  + 25165824;               // 25165824
  short* Vtw = Kw  + 25165824;               // 25165824  (total ~243 MB)

  cvt_x<<<24576, 256, 0, stream>>>(from_t, to_t, fb, tb);
  cvt_w<<<6912, 256, 0, stream>>>(Wq, Wk, Wv, Wt);
  qkv_gemm<<<4608, 256, 0, stream>>>(fb, tb, Wt, bq, bk, bv, Qw, Kw, Vtw);
  attn_kernel<<<6144, 256, 147456, stream>>>(Qw, Kw, Vtw, (float*)d_out);
}

// Round 2
// 394.137 us; speedup vs baseline: 1.2100x; 1.2100x over previous
//
#include <hip/hip_runtime.h>
#include <hip/hip_bf16.h>

#define GAS __attribute__((address_space(1)))
#define LAS __attribute__((address_space(3)))

typedef __attribute__((ext_vector_type(8))) short   bf16x8;
typedef __attribute__((ext_vector_type(4))) float   f32x4;
typedef __attribute__((ext_vector_type(4))) float   f4;
typedef __attribute__((ext_vector_type(8))) short   s8v;
typedef __attribute__((ext_vector_type(2))) unsigned int u32x2;

#define NB  64
#define NS  512
#define ND  768
#define NH  12
#define NHS 64
#define NM  (NB*NS)    /* 32768 */
#define NBH (NB*NH)    /* 768   */

// 0.125 * log2(e): folded into Q so softmax uses exp2 directly
#define QSCALE 0.18033688011112042f

__device__ __forceinline__ unsigned short f2bf(float x){
  unsigned int u = __float_as_uint(x);
  u += 0x7fffu + ((u >> 16) & 1u);       // round-to-nearest-even
  return (unsigned short)(u >> 16);
}

__device__ __forceinline__ f32x4 mfma16(bf16x8 a, bf16x8 b, f32x4 c){
  return __builtin_amdgcn_mfma_f32_16x16x32_bf16(a, b, c, 0, 0, 0);
}

// ---------------- fp32 -> bf16 convert of activations ----------------
__global__ void cvt_x(const float* __restrict__ from_t, const float* __restrict__ to_t,
                      short* __restrict__ fb, short* __restrict__ tb){
  int v = blockIdx.x * 256 + threadIdx.x;          // one thread = 8 elems
  const int NG = NM * ND / 8;                      // 3145728 per tensor
  const float* s; short* d;
  if (v < NG){ s = from_t; d = fb; } else { s = to_t; d = tb; v -= NG; }
  f4 a = ((const f4*)s)[(long)v * 2];
  f4 b = ((const f4*)s)[(long)v * 2 + 1];
  s8v o;
  o[0]=(short)f2bf(a[0]); o[1]=(short)f2bf(a[1]); o[2]=(short)f2bf(a[2]); o[3]=(short)f2bf(a[3]);
  o[4]=(short)f2bf(b[0]); o[5]=(short)f2bf(b[1]); o[6]=(short)f2bf(b[2]); o[7]=(short)f2bf(b[3]);
  ((s8v*)d)[v] = o;
}

// ---------------- W [k][n] fp32 -> Wt [mat][n][k] bf16 ----------------
__global__ void cvt_w(const float* __restrict__ Wq, const float* __restrict__ Wk,
                      const float* __restrict__ Wv, short* __restrict__ Wt){
  int i = blockIdx.x * 256 + threadIdx.x;          // 0 .. 3*768*768-1
  int mat = i / (ND*ND);
  int rem = i - mat * (ND*ND);
  int k = rem / ND;
  int n = rem - k * ND;
  const float* W = (mat == 0) ? Wq : (mat == 1 ? Wk : Wv);
  Wt[(long)mat*ND*ND + (long)n*ND + k] = (short)f2bf(W[rem]);
}

// ---------------- fused QKV GEMM: [32768,768] x [768,768] + bias ----------------
// A (activations) bf16 row-major; Wt bf16 [n][k]; out Q (pre-scaled by QSCALE)
// and K as [b,h,s,hs] bf16, V as [b,h,hs,s] bf16 (pre-transposed for PV).
__global__ __launch_bounds__(256, 2)
void qkv_gemm(const short* __restrict__ Xf, const short* __restrict__ Xt,
              const short* __restrict__ Wt,
              const float* __restrict__ bq, const float* __restrict__ bk,
              const float* __restrict__ bv,
              short* __restrict__ Qw, short* __restrict__ Kw, short* __restrict__ Vtw){
  __shared__ short As[2][128*64];   // 16 KB each buf
  __shared__ short Bs[2][128*64];

  int bid = blockIdx.x;                       // 4608 blocks, 4608%8==0
  int wg  = (bid & 7) * 576 + (bid >> 3);     // XCD-contiguous chunks
  int mat = wg / 1536;
  int r   = wg - mat * 1536;
  int mt  = r / 6;
  int nt  = r - mt * 6;

  const short* A  = (mat == 0) ? Xf : Xt;
  const short* W  = Wt + (long)mat * ND * ND;
  const float* bias = (mat == 0) ? bq : (mat == 1 ? bk : bv);

  int t = threadIdx.x, wv = t >> 6, l = t & 63, g = l >> 4, c = l & 15;
  int wm = wv >> 1, wn = wv & 1;
  int m0 = mt * 128, n0 = nt * 128;

  auto stage = [&](int buf, int kt){
    #pragma unroll
    for (int it = 0; it < 4; ++it){
      int chunk = it * 4 + wv;                 // wave-uniform
      int idx = chunk * 64 + l;
      int row = idx >> 3, slot = idx & 7;      // 128 rows x 8 slots of 16B
      const short* ga = A + (long)(m0 + row) * ND + kt * 64 + ((slot ^ (row & 7)) * 8);
      __builtin_amdgcn_global_load_lds((const GAS unsigned int*)ga,
                                       (LAS unsigned int*)(&As[buf][chunk * 512]), 16, 0, 0);
      const short* gb = W + (long)(n0 + row) * ND + kt * 64 + ((slot ^ (row & 7)) * 8);
      __builtin_amdgcn_global_load_lds((const GAS unsigned int*)gb,
                                       (LAS unsigned int*)(&Bs[buf][chunk * 512]), 16, 0, 0);
    }
  };

  f32x4 zero = {0.f, 0.f, 0.f, 0.f};
  f32x4 acc[4][4];
  #pragma unroll
  for (int i = 0; i < 4; ++i)
    #pragma unroll
    for (int j = 0; j < 4; ++j) acc[i][j] = zero;

  stage(0, 0);
  __syncthreads();
  int buf = 0;
  for (int kt = 0; kt < 12; ++kt){
    if (kt < 11) stage(buf ^ 1, kt + 1);
    #pragma unroll
    for (int kk = 0; kk < 2; ++kk){
      bf16x8 af[4], bfv[4];
      #pragma unroll
      for (int ms = 0; ms < 4; ++ms){
        int row = wm * 64 + ms * 16 + c;
        af[ms] = *(const bf16x8*)((const char*)&As[buf][0] + row * 128 +
                                  (((kk * 4 + g) ^ (row & 7)) << 4));
      }
      #pragma unroll
      for (int ns = 0; ns < 4; ++ns){
        int row = wn * 64 + ns * 16 + c;
        bfv[ns] = *(const bf16x8*)((const char*)&Bs[buf][0] + row * 128 +
                                   (((kk * 4 + g) ^ (row & 7)) << 4));
      }
      #pragma unroll
      for (int ms = 0; ms < 4; ++ms)
        #pragma unroll
        for (int ns = 0; ns < 4; ++ns)
          acc[ms][ns] = mfma16(af[ms], bfv[ns], acc[ms][ns]);
    }
    __syncthreads();
    buf ^= 1;
  }

  // Epilogue: C row = wm*64+ms*16+g*4+i (s index), col = wn*64+ns*16+c (h,hs)
  if (mat < 2){
    short* O = (mat == 0) ? Qw : Kw;
    float scl = (mat == 0) ? QSCALE : 1.0f;
    #pragma unroll
    for (int ms = 0; ms < 4; ++ms){
      #pragma unroll
      for (int ns = 0; ns < 4; ++ns){
        int n = n0 + wn * 64 + ns * 16 + c;
        int h = n >> 6, hs = n & 63;
        float bb = bias[n];
        #pragma unroll
        for (int i = 0; i < 4; ++i){
          int m = m0 + wm * 64 + ms * 16 + g * 4 + i;
          int b = m >> 9, s = m & 511;
          O[(((long)(b * NH + h) * NS + s) << 6) + hs] = (short)f2bf((acc[ms][ns][i] + bb) * scl);
        }
      }
    }
  } else {
    #pragma unroll
    for (int ms = 0; ms < 4; ++ms){
      #pragma unroll
      for (int ns = 0; ns < 4; ++ns){
        int n = n0 + wn * 64 + ns * 16 + c;
        int h = n >> 6, hs = n & 63;
        float bb = bias[n];
        int m = m0 + wm * 64 + ms * 16 + g * 4;   // 4 consecutive s per lane
        int b = m >> 9, s = m & 511;
        unsigned int p0 = (unsigned int)f2bf(acc[ms][ns][0]  + bb) |
                          ((unsigned int)f2bf(acc[ms][ns][1] + bb) << 16);
        unsigned int p1 = (unsigned int)f2bf(acc[ms][ns][2]  + bb) |
                          ((unsigned int)f2bf(acc[ms][ns][3] + bb) << 16);
        u32x2 pk; pk[0] = p0; pk[1] = p1;
        short* dst = Vtw + ((long)(b * NH + h) * 64 + hs) * NS + s;
        *(u32x2*)dst = pk;                        // 8B store, s%4==0 -> aligned
      }
    }
  }
}

// ---------------- attention v2: one (b,h) per block, 8 waves, K/V staged ONCE ----------------
__global__ __launch_bounds__(512, 1)
void attn_kernel(const short* __restrict__ Qw, const short* __restrict__ Kw,
                 const short* __restrict__ Vtw, float* __restrict__ out){
  extern __shared__ char smem[];
  short* Ks = (short*)smem;              // [512][64] bf16, swizzled rows 128B, 64 KB
  short* Vs = (short*)(smem + 65536);    // [64][512] bf16, swizzled rows 1KB, 64 KB
  short* Ps = (short*)(smem + 131072);   // 8 waves x [16][64] bf16 (2KB each), 16 KB

  int bh = blockIdx.x;                   // 768 blocks
  int t = threadIdx.x, wv = t >> 6, l = t & 63, g = l >> 4, c = l & 15;

  const short* Kb = Kw  + (long)bh * NS * NHS;
  const short* Vb = Vtw + (long)bh * NS * NHS;

  // stage K [key][d] and Vt [d][key] once, 128 chunks of 1KB over 8 waves
  #pragma unroll
  for (int it = 0; it < 8; ++it){
    int chunk = it * 8 + wv;             // wave-uniform, 0..63
    {
      int idx = chunk * 64 + l;
      int row = idx >> 3, slot = idx & 7;
      const short* gk = Kb + row * 64 + ((slot ^ (row & 7)) * 8);
      __builtin_amdgcn_global_load_lds((const GAS unsigned int*)gk,
                                       (LAS unsigned int*)(Ks + chunk * 512), 16, 0, 0);
    }
    {
      int row = chunk, slot = l;         // one chunk = one d-row
      const short* gv = Vb + (long)row * NS + (((slot & 56) | ((slot & 7) ^ (row & 7))) * 8);
      __builtin_amdgcn_global_load_lds((const GAS unsigned int*)gv,
                                       (LAS unsigned int*)(Vs + chunk * 512), 16, 0, 0);
    }
  }
  __syncthreads();

  short* Pw = Ps + wv * 1024;            // this wave's [16][64] chunk, rows 128B
  int b = bh / NH, h = bh - b * NH;
  float* outb = out + (long)b * NS * ND + (long)h * 64;

  f32x4 zero = {0.f, 0.f, 0.f, 0.f};

  // each wave owns q-tile [wv*64, wv*64+64), loops 4 q-groups of 16 rows
  for (int qg = 0; qg < 4; ++qg){
    int q0 = wv * 64 + qg * 16;
    const short* Qb = Qw + ((long)bh * NS + q0 + c) * 64;
    bf16x8 aq0 = *(const bf16x8*)(Qb + g * 8);
    bf16x8 aq1 = *(const bf16x8*)(Qb + 32 + g * 8);

    // ---- scores (pre-scaled by QSCALE upstream): sc[j][i] = S'[q=g*4+i][key=j*16+c]
    f32x4 sc[32];
    #pragma unroll
    for (int j = 0; j < 32; ++j) sc[j] = zero;

    #pragma unroll
    for (int j = 0; j < 32; ++j){
      int key = j * 16 + c;
      const char* base = (const char*)Ks + key * 128;
      bf16x8 b0 = *(const bf16x8*)(base + (((0 + g) ^ (key & 7)) << 4));
      bf16x8 b1 = *(const bf16x8*)(base + (((4 + g) ^ (key & 7)) << 4));
      sc[j] = mfma16(aq0, b0, sc[j]);
      sc[j] = mfma16(aq1, b1, sc[j]);
    }

    // ---- softmax (exp2 domain; P left unnormalized, 1/sum deferred to epilogue)
    float inv[4];
    #pragma unroll
    for (int i = 0; i < 4; ++i){
      float m = sc[0][i];
      #pragma unroll
      for (int j = 1; j < 32; ++j) m = fmaxf(m, sc[j][i]);
      m = fmaxf(m, __shfl_xor(m, 1));
      m = fmaxf(m, __shfl_xor(m, 2));
      m = fmaxf(m, __shfl_xor(m, 4));
      m = fmaxf(m, __shfl_xor(m, 8));
      float s_ = 0.f;
      #pragma unroll
      for (int j = 0; j < 32; ++j){
        float p = exp2f(sc[j][i] - m);
        sc[j][i] = p;
        s_ += p;
      }
      s_ += __shfl_xor(s_, 1);
      s_ += __shfl_xor(s_, 2);
      s_ += __shfl_xor(s_, 4);
      s_ += __shfl_xor(s_, 8);
      inv[i] = 1.f / s_;
    }

    // ---- PV through wave-private P chunks (64 keys per chunk, no barriers)
    f32x4 o[4];
    #pragma unroll
    for (int ns = 0; ns < 4; ++ns) o[ns] = zero;

    #pragma unroll
    for (int ch = 0; ch < 8; ++ch){
      #pragma unroll
      for (int jl = 0; jl < 4; ++jl){
        int kl = jl * 16 + c;
        int slot = kl >> 3;
        #pragma unroll
        for (int i = 0; i < 4; ++i){
          int q = g * 4 + i;
          int byte = q * 128 + ((slot ^ (q & 7)) << 4) + ((kl & 7) << 1);
          *(short*)((char*)Pw + byte) = (short)f2bf(sc[ch * 4 + jl][i]);
        }
      }
      #pragma unroll
      for (int kk = 0; kk < 2; ++kk){
        int slotp = kk * 4 + g;
        bf16x8 ap = *(const bf16x8*)((const char*)Pw + c * 128 + ((slotp ^ (c & 7)) << 4));
        #pragma unroll
        for (int ns = 0; ns < 4; ++ns){
          int d = ns * 16 + c;
          int slotv = ch * 8 + kk * 4 + g;
          bf16x8 bv8 = *(const bf16x8*)((const char*)Vs + d * 1024 +
                                        (((slotv & 56) | ((slotv & 7) ^ (d & 7))) << 4));
          o[ns] = mfma16(ap, bv8, o[ns]);
        }
      }
    }

    // ---- write fp32 output [b,q,h*64+d], applying deferred 1/sum
    #pragma unroll
    for (int ns = 0; ns < 4; ++ns)
      #pragma unroll
      for (int i = 0; i < 4; ++i){
        int q = q0 + g * 4 + i;
        outb[(long)q * ND + ns * 16 + c] = o[ns][i] * inv[i];
      }
  }
}

// ---------------- launch ----------------
extern "C" void kernel_launch(void* const* d_in, const int* in_sizes, int n_in,
                              void* d_out, int out_size, void* d_ws, size_t ws_size,
                              hipStream_t stream){
  const float* from_t = (const float*)d_in[0];
  const float* to_t   = (const float*)d_in[1];
  const float* Wq = (const float*)d_in[2];
  const float* bq = (const float*)d_in[3];
  const float* Wk = (const float*)d_in[4];
  const float* bk = (const float*)d_in[5];
  const float* Wv = (const float*)d_in[6];
  const float* bv = (const float*)d_in[7];

  short* fb  = (short*)d_ws;                 // 25165824 bf16
  short* tb  = fb  + 25165824;               // 25165824
  short* Wt  = tb  + 25165824;               // 1769472
  short* Qw  = Wt  + 1769472;                // 25165824
  short* Kw  = Qw  + 25165824;               // 25165824
  short* Vtw = Kw  + 25165824;               // 25165824  (total ~243 MB)

  cvt_x<<<24576, 256, 0, stream>>>(from_t, to_t, fb, tb);
  cvt_w<<<6912, 256, 0, stream>>>(Wq, Wk, Wv, Wt);
  qkv_gemm<<<4608, 256, 0, stream>>>(fb, tb, Wt, bq, bk, bv, Qw, Kw, Vtw);
  attn_kernel<<<768, 512, 147456, stream>>>(Qw, Kw, Vtw, (float*)d_out);
}

// Round 4
// 350.669 us; speedup vs baseline: 1.3600x; 1.1240x over previous
//
#include <hip/hip_runtime.h>
#include <hip/hip_bf16.h>

#define GAS __attribute__((address_space(1)))
#define LAS __attribute__((address_space(3)))

typedef __attribute__((ext_vector_type(8))) short   bf16x8;
typedef __attribute__((ext_vector_type(4))) float   f32x4;
typedef __attribute__((ext_vector_type(4))) float   f4;
typedef __attribute__((ext_vector_type(8))) short   s8v;
typedef __attribute__((ext_vector_type(2))) unsigned int u32x2;

#define NB  64
#define NS  512
#define ND  768
#define NH  12
#define NHS 64
#define NM  (NB*NS)    /* 32768 */
#define NBH (NB*NH)    /* 768   */

// 0.125 * log2(e): folded into Q so softmax uses exp2 directly
#define QSCALE 0.18033688011112042f

__device__ __forceinline__ unsigned short f2bf(float x){
  unsigned int u = __float_as_uint(x);
  u += 0x7fffu + ((u >> 16) & 1u);       // round-to-nearest-even
  return (unsigned short)(u >> 16);
}

__device__ __forceinline__ f32x4 mfma16(bf16x8 a, bf16x8 b, f32x4 c){
  return __builtin_amdgcn_mfma_f32_16x16x32_bf16(a, b, c, 0, 0, 0);
}

// ---------------- fp32 -> bf16 convert of activations ----------------
__global__ void cvt_x(const float* __restrict__ from_t, const float* __restrict__ to_t,
                      short* __restrict__ fb, short* __restrict__ tb){
  int v = blockIdx.x * 256 + threadIdx.x;          // one thread = 8 elems
  const int NG = NM * ND / 8;                      // 3145728 per tensor
  const float* s; short* d;
  if (v < NG){ s = from_t; d = fb; } else { s = to_t; d = tb; v -= NG; }
  f4 a = ((const f4*)s)[(long)v * 2];
  f4 b = ((const f4*)s)[(long)v * 2 + 1];
  s8v o;
  o[0]=(short)f2bf(a[0]); o[1]=(short)f2bf(a[1]); o[2]=(short)f2bf(a[2]); o[3]=(short)f2bf(a[3]);
  o[4]=(short)f2bf(b[0]); o[5]=(short)f2bf(b[1]); o[6]=(short)f2bf(b[2]); o[7]=(short)f2bf(b[3]);
  ((s8v*)d)[v] = o;
}

// ---------------- W [k][n] fp32 -> Wt [mat][n][k] bf16 ----------------
__global__ void cvt_w(const float* __restrict__ Wq, const float* __restrict__ Wk,
                      const float* __restrict__ Wv, short* __restrict__ Wt){
  int i = blockIdx.x * 256 + threadIdx.x;          // 0 .. 3*768*768-1
  int mat = i / (ND*ND);
  int rem = i - mat * (ND*ND);
  int k = rem / ND;
  int n = rem - k * ND;
  const float* W = (mat == 0) ? Wq : (mat == 1 ? Wk : Wv);
  Wt[(long)mat*ND*ND + (long)n*ND + k] = (short)f2bf(W[rem]);
}

// ---------------- fused QKV GEMM v2: 256x256 tile, BK=32, triple-buffered,
// counted vmcnt(4) pipeline, one raw s_barrier per K-step, setprio MFMA,
// LDS-shuffle coalesced epilogue. ----------------
__global__ __launch_bounds__(512, 2)
void qkv_gemm(const short* __restrict__ Xf, const short* __restrict__ Xt,
              const short* __restrict__ Wt,
              const float* __restrict__ bq, const float* __restrict__ bk,
              const float* __restrict__ bv,
              short* __restrict__ Qw, short* __restrict__ Kw, short* __restrict__ Vtw){
  __shared__ short smem[49152];   // 96 KB: A slots @ s*8192, B slots @ 24576 + s*8192

  int bid = blockIdx.x;                       // 1152 blocks, %8==0
  int wg  = (bid & 7) * 144 + (bid >> 3);     // XCD-contiguous chunks
  int mat = wg / 384;
  int r   = wg - mat * 384;
  int mt  = r / 3;
  int nt  = r - mt * 3;                       // nt fastest: neighbors share A-panel

  const short* A  = (mat == 0) ? Xf : Xt;
  const short* Wp = Wt + (long)mat * ND * ND;

  int t_ = threadIdx.x, wv = t_ >> 6, l = t_ & 63, g = l >> 4, c = l & 15;
  int wm = wv >> 2, wn = wv & 3;              // 2M x 4N waves, 128x64 per wave
  int m0 = mt * 256, n0 = nt * 256;

  short* As[3] = { smem, smem + 8192, smem + 16384 };
  short* Bs[3] = { smem + 24576, smem + 32768, smem + 40960 };

  // stage one quarter (ci) of K-tile kt: A chunks 0..15, B chunks 16..31 (1KB each)
  auto stage = [&](int kt, short* Ab, short* Bb, int ci){
    int chunk = ci * 8 + wv;                  // wave-uniform
    int ch = chunk & 15;
    int idx = ch * 64 + l;
    int row = idx >> 2, slot = idx & 3;       // 256 rows x 4 slots of 16B
    int kcol = kt * 32 + ((slot ^ ((row >> 1) & 3)) << 3);
    if (chunk < 16){
      const short* gp = A + (long)(m0 + row) * ND + kcol;
      __builtin_amdgcn_global_load_lds((const GAS unsigned int*)gp,
                                       (LAS unsigned int*)(Ab + ch * 512), 16, 0, 0);
    } else {
      const short* gp = Wp + (long)(n0 + row) * ND + kcol;
      __builtin_amdgcn_global_load_lds((const GAS unsigned int*)gp,
                                       (LAS unsigned int*)(Bb + ch * 512), 16, 0, 0);
    }
  };

  f32x4 zero = {0.f, 0.f, 0.f, 0.f};
  f32x4 acc[8][4];
  #pragma unroll
  for (int i = 0; i < 8; ++i)
    #pragma unroll
    for (int j = 0; j < 4; ++j) acc[i][j] = zero;

  // prologue: K-tiles 0,1 in flight
  #pragma unroll
  for (int ci = 0; ci < 4; ++ci) stage(0, As[0], Bs[0], ci);
  #pragma unroll
  for (int ci = 0; ci < 4; ++ci) stage(1, As[1], Bs[1], ci);

  auto step = [&](const short* Asl, const short* Bsl, short* An, short* Bn, int t){
    if (t == 23) asm volatile("s_waitcnt vmcnt(0)" ::: "memory");
    else         asm volatile("s_waitcnt vmcnt(4)" ::: "memory");
    __builtin_amdgcn_s_barrier();
    bf16x8 af[8], bfr[4];
    #pragma unroll
    for (int ms = 0; ms < 4; ++ms){
      int row = wm * 128 + ms * 16 + c;
      af[ms] = *(const bf16x8*)(Asl + row * 32 + ((g ^ ((row >> 1) & 3)) << 3));
    }
    if (t < 22) stage(t + 2, An, Bn, 0);
    #pragma unroll
    for (int ns = 0; ns < 4; ++ns){
      int row = wn * 64 + ns * 16 + c;
      bfr[ns] = *(const bf16x8*)(Bsl + row * 32 + ((g ^ ((row >> 1) & 3)) << 3));
    }
    if (t < 22) stage(t + 2, An, Bn, 1);
    #pragma unroll
    for (int ms = 4; ms < 8; ++ms){
      int row = wm * 128 + ms * 16 + c;
      af[ms] = *(const bf16x8*)(Asl + row * 32 + ((g ^ ((row >> 1) & 3)) << 3));
    }
    if (t < 22){ stage(t + 2, An, Bn, 2); stage(t + 2, An, Bn, 3); }
    __builtin_amdgcn_s_setprio(1);
    #pragma unroll
    for (int ms = 0; ms < 8; ++ms)
      #pragma unroll
      for (int ns = 0; ns < 4; ++ns)
        acc[ms][ns] = mfma16(af[ms], bfr[ns], acc[ms][ns]);
    __builtin_amdgcn_s_setprio(0);
  };

  for (int it = 0; it < 8; ++it){
    int t = it * 3;
    step(As[0], Bs[0], As[2], Bs[2], t);
    step(As[1], Bs[1], As[0], Bs[0], t + 1);
    step(As[2], Bs[2], As[1], Bs[1], t + 2);
  }

  __builtin_amdgcn_s_barrier();              // all K-loop LDS reads done everywhere

  // ---- epilogue: wave-private 8KB LDS chunk -> coalesced 16B stores
  int n0g = n0 + wn * 64;                    // 64 cols = exactly one head
  const float* bias = (mat == 0) ? bq : (mat == 1 ? bk : bv);
  float bb[4];
  #pragma unroll
  for (int ns = 0; ns < 4; ++ns) bb[ns] = bias[n0g + ns * 16 + c];
  short* chunk = smem + wv * 4096;           // 8 KB per wave
  int hq = n0g >> 6;

  if (mat < 2){
    short* O = (mat == 0) ? Qw : Kw;
    float scl = (mat == 0) ? QSCALE : 1.0f;
    #pragma unroll
    for (int sp = 0; sp < 2; ++sp){
      #pragma unroll
      for (int msl = 0; msl < 4; ++msl){
        #pragma unroll
        for (int ns = 0; ns < 4; ++ns){
          int col = ns * 16 + c;             // hs
          #pragma unroll
          for (int i = 0; i < 4; ++i){
            int row = msl * 16 + g * 4 + i;  // s-local 0..63
            chunk[row * 64 + (((col >> 3) ^ (row & 7)) << 3) + (col & 7)] =
                (short)f2bf((acc[sp * 4 + msl][ns][i] + bb[ns]) * scl);
          }
        }
      }
      asm volatile("s_waitcnt lgkmcnt(0)" ::: "memory");
      __builtin_amdgcn_sched_barrier(0);
      #pragma unroll
      for (int rr = 0; rr < 8; ++rr){
        int row = rr * 8 + (l >> 3);         // 0..63, all 64 rows covered
        int slot = l & 7;
        bf16x8 v = *(const bf16x8*)(chunk + row * 64 + ((slot ^ (row & 7)) << 3));
        int m = m0 + wm * 128 + sp * 64 + row;
        int b = m >> 9, s2 = m & 511;
        *(bf16x8*)(O + (((long)(b * NH + hq) * NS + s2) << 6) + slot * 8) = v;
      }
      if (sp == 0){ asm volatile("s_waitcnt lgkmcnt(0)" ::: "memory"); }
    }
  } else {
    #pragma unroll
    for (int sp = 0; sp < 2; ++sp){
      #pragma unroll
      for (int msl = 0; msl < 4; ++msl){
        #pragma unroll
        for (int ns = 0; ns < 4; ++ns){
          int hs = ns * 16 + c;              // row 0..63
          #pragma unroll
          for (int i = 0; i < 4; ++i){
            int col = msl * 16 + g * 4 + i;  // s-local 0..63
            chunk[hs * 64 + (((col >> 3) ^ (hs & 7)) << 3) + (col & 7)] =
                (short)f2bf(acc[sp * 4 + msl][ns][i] + bb[ns]);
          }
        }
      }
      asm volatile("s_waitcnt lgkmcnt(0)" ::: "memory");
      __builtin_amdgcn_sched_barrier(0);
      int mbase = m0 + wm * 128 + sp * 64;   // 64-aligned, never crosses b
      int b = mbase >> 9, s0 = mbase & 511;
      #pragma unroll
      for (int rr = 0; rr < 8; ++rr){
        int hs = rr * 8 + (l >> 3);
        int slot = l & 7;
        bf16x8 v = *(const bf16x8*)(chunk + hs * 64 + ((slot ^ (hs & 7)) << 3));
        *(bf16x8*)(Vtw + (long)((b * NH + hq) * 64 + hs) * NS + s0 + slot * 8) = v;
      }
      if (sp == 0){ asm volatile("s_waitcnt lgkmcnt(0)" ::: "memory"); }
    }
  }
}

// ---------------- attention: one (b,h) per block, 8 waves, K/V staged ONCE ----------------
__global__ __launch_bounds__(512, 1)
void attn_kernel(const short* __restrict__ Qw, const short* __restrict__ Kw,
                 const short* __restrict__ Vtw, float* __restrict__ out){
  extern __shared__ char smem[];
  short* Ks = (short*)smem;              // [512][64] bf16, swizzled rows 128B, 64 KB
  short* Vs = (short*)(smem + 65536);    // [64][512] bf16, swizzled rows 1KB, 64 KB
  short* Ps = (short*)(smem + 131072);   // 8 waves x [16][64] bf16 (2KB each), 16 KB

  int bh = blockIdx.x;                   // 768 blocks
  int t = threadIdx.x, wv = t >> 6, l = t & 63, g = l >> 4, c = l & 15;

  const short* Kb = Kw  + (long)bh * NS * NHS;
  const short* Vb = Vtw + (long)bh * NS * NHS;

  // stage K [key][d] and Vt [d][key] once, 128 chunks of 1KB over 8 waves
  #pragma unroll
  for (int it = 0; it < 8; ++it){
    int chunk = it * 8 + wv;             // wave-uniform, 0..63
    {
      int idx = chunk * 64 + l;
      int row = idx >> 3, slot = idx & 7;
      const short* gk = Kb + row * 64 + ((slot ^ (row & 7)) * 8);
      __builtin_amdgcn_global_load_lds((const GAS unsigned int*)gk,
                                       (LAS unsigned int*)(Ks + chunk * 512), 16, 0, 0);
    }
    {
      int row = chunk, slot = l;         // one chunk = one d-row
      const short* gv = Vb + (long)row * NS + (((slot & 56) | ((slot & 7) ^ (row & 7))) * 8);
      __builtin_amdgcn_global_load_lds((const GAS unsigned int*)gv,
                                       (LAS unsigned int*)(Vs + chunk * 512), 16, 0, 0);
    }
  }
  __syncthreads();

  short* Pw = Ps + wv * 1024;            // this wave's [16][64] chunk, rows 128B
  int b = bh / NH, h = bh - b * NH;
  float* outb = out + (long)b * NS * ND + (long)h * 64;

  f32x4 zero = {0.f, 0.f, 0.f, 0.f};

  // each wave owns q-tile [wv*64, wv*64+64), loops 4 q-groups of 16 rows
  for (int qg = 0; qg < 4; ++qg){
    int q0 = wv * 64 + qg * 16;
    const short* Qb = Qw + ((long)bh * NS + q0 + c) * 64;
    bf16x8 aq0 = *(const bf16x8*)(Qb + g * 8);
    bf16x8 aq1 = *(const bf16x8*)(Qb + 32 + g * 8);

    // ---- scores (pre-scaled by QSCALE upstream): sc[j][i] = S'[q=g*4+i][key=j*16+c]
    f32x4 sc[32];
    #pragma unroll
    for (int j = 0; j < 32; ++j) sc[j] = zero;

    #pragma unroll
    for (int j = 0; j < 32; ++j){
      int key = j * 16 + c;
      const char* base = (const char*)Ks + key * 128;
      bf16x8 b0 = *(const bf16x8*)(base + (((0 + g) ^ (key & 7)) << 4));
      bf16x8 b1 = *(const bf16x8*)(base + (((4 + g) ^ (key & 7)) << 4));
      sc[j] = mfma16(aq0, b0, sc[j]);
      sc[j] = mfma16(aq1, b1, sc[j]);
    }

    // ---- softmax (exp2 domain; P left unnormalized, 1/sum deferred to epilogue)
    float inv[4];
    #pragma unroll
    for (int i = 0; i < 4; ++i){
      float m = sc[0][i];
      #pragma unroll
      for (int j = 1; j < 32; ++j) m = fmaxf(m, sc[j][i]);
      m = fmaxf(m, __shfl_xor(m, 1));
      m = fmaxf(m, __shfl_xor(m, 2));
      m = fmaxf(m, __shfl_xor(m, 4));
      m = fmaxf(m, __shfl_xor(m, 8));
      float s_ = 0.f;
      #pragma unroll
      for (int j = 0; j < 32; ++j){
        float p = exp2f(sc[j][i] - m);
        sc[j][i] = p;
        s_ += p;
      }
      s_ += __shfl_xor(s_, 1);
      s_ += __shfl_xor(s_, 2);
      s_ += __shfl_xor(s_, 4);
      s_ += __shfl_xor(s_, 8);
      inv[i] = 1.f / s_;
    }

    // ---- PV through wave-private P chunks (64 keys per chunk, no barriers)
    f32x4 o[4];
    #pragma unroll
    for (int ns = 0; ns < 4; ++ns) o[ns] = zero;

    #pragma unroll
    for (int ch = 0; ch < 8; ++ch){
      #pragma unroll
      for (int jl = 0; jl < 4; ++jl){
        int kl = jl * 16 + c;
        int slot = kl >> 3;
        #pragma unroll
        for (int i = 0; i < 4; ++i){
          int q = g * 4 + i;
          int byte = q * 128 + ((slot ^ (q & 7)) << 4) + ((kl & 7) << 1);
          *(short*)((char*)Pw + byte) = (short)f2bf(sc[ch * 4 + jl][i]);
        }
      }
      #pragma unroll
      for (int kk = 0; kk < 2; ++kk){
        int slotp = kk * 4 + g;
        bf16x8 ap = *(const bf16x8*)((const char*)Pw + c * 128 + ((slotp ^ (c & 7)) << 4));
        #pragma unroll
        for (int ns = 0; ns < 4; ++ns){
          int d = ns * 16 + c;
          int slotv = ch * 8 + kk * 4 + g;
          bf16x8 bv8 = *(const bf16x8*)((const char*)Vs + d * 1024 +
                                        (((slotv & 56) | ((slotv & 7) ^ (d & 7))) << 4));
          o[ns] = mfma16(ap, bv8, o[ns]);
        }
      }
    }

    // ---- write fp32 output [b,q,h*64+d], applying deferred 1/sum
    #pragma unroll
    for (int ns = 0; ns < 4; ++ns)
      #pragma unroll
      for (int i = 0; i < 4; ++i){
        int q = q0 + g * 4 + i;
        outb[(long)q * ND + ns * 16 + c] = o[ns][i] * inv[i];
      }
  }
}

// ---------------- launch ----------------
extern "C" void kernel_launch(void* const* d_in, const int* in_sizes, int n_in,
                              void* d_out, int out_size, void* d_ws, size_t ws_size,
                              hipStream_t stream){
  const float* from_t = (const float*)d_in[0];
  const float* to_t   = (const float*)d_in[1];
  const float* Wq = (const float*)d_in[2];
  const float* bq = (const float*)d_in[3];
  const float* Wk = (const float*)d_in[4];
  const float* bk = (const float*)d_in[5];
  const float* Wv = (const float*)d_in[6];
  const float* bv = (const float*)d_in[7];

  short* fb  = (short*)d_ws;                 // 25165824 bf16
  short* tb  = fb  + 25165824;               // 25165824
  short* Wt  = tb  + 25165824;               // 1769472
  short* Qw  = Wt  + 1769472;                // 25165824
  short* Kw  = Qw  + 25165824;               // 25165824
  short* Vtw = Kw  + 25165824;               // 25165824  (total ~243 MB)

  cvt_x<<<24576, 256, 0, stream>>>(from_t, to_t, fb, tb);
  cvt_w<<<6912, 256, 0, stream>>>(Wq, Wk, Wv, Wt);
  qkv_gemm<<<1152, 512, 0, stream>>>(fb, tb, Wt, bq, bk, bv, Qw, Kw, Vtw);
  attn_kernel<<<768, 512, 147456, stream>>>(Qw, Kw, Vtw, (float*)d_out);
}

// Round 5
// 330.948 us; speedup vs baseline: 1.4410x; 1.0596x over previous
//
#include <hip/hip_runtime.h>
#include <hip/hip_bf16.h>

#define GAS __attribute__((address_space(1)))
#define LAS __attribute__((address_space(3)))

typedef __attribute__((ext_vector_type(8))) short   bf16x8;
typedef __attribute__((ext_vector_type(4))) float   f32x4;
typedef __attribute__((ext_vector_type(16))) float  f32x16;
typedef __attribute__((ext_vector_type(4))) float   f4;
typedef __attribute__((ext_vector_type(8))) short   s8v;
typedef __attribute__((ext_vector_type(2))) unsigned int u32x2;
typedef __attribute__((ext_vector_type(4))) unsigned int u32x4;

#define NB  64
#define NS  512
#define ND  768
#define NH  12
#define NHS 64
#define NM  (NB*NS)    /* 32768 */
#define NBH (NB*NH)    /* 768   */

// 0.125 * log2(e): folded into Q so softmax uses exp2 directly
#define QSCALE 0.18033688011112042f

__device__ __forceinline__ unsigned short f2bf(float x){
  unsigned int u = __float_as_uint(x);
  u += 0x7fffu + ((u >> 16) & 1u);       // round-to-nearest-even
  return (unsigned short)(u >> 16);
}

__device__ __forceinline__ f32x4 mfma16(bf16x8 a, bf16x8 b, f32x4 c){
  return __builtin_amdgcn_mfma_f32_16x16x32_bf16(a, b, c, 0, 0, 0);
}

__device__ __forceinline__ f32x16 mfma32(bf16x8 a, bf16x8 b, f32x16 c){
  return __builtin_amdgcn_mfma_f32_32x32x16_bf16(a, b, c, 0, 0, 0);
}

__device__ __forceinline__ unsigned int cvtpk(float lo, float hi){
  unsigned int r;
  asm("v_cvt_pk_bf16_f32 %0, %1, %2" : "=v"(r) : "v"(lo), "v"(hi));
  return r;
}

__device__ __forceinline__ bf16x8 u2b(u32x4 u){
  union { u32x4 a; bf16x8 b; } c; c.a = u; return c.b;
}

// ---------------- fp32 -> bf16 convert of activations ----------------
__global__ void cvt_x(const float* __restrict__ from_t, const float* __restrict__ to_t,
                      short* __restrict__ fb, short* __restrict__ tb){
  int v = blockIdx.x * 256 + threadIdx.x;          // one thread = 8 elems
  const int NG = NM * ND / 8;                      // 3145728 per tensor
  const float* s; short* d;
  if (v < NG){ s = from_t; d = fb; } else { s = to_t; d = tb; v -= NG; }
  f4 a = ((const f4*)s)[(long)v * 2];
  f4 b = ((const f4*)s)[(long)v * 2 + 1];
  s8v o;
  o[0]=(short)f2bf(a[0]); o[1]=(short)f2bf(a[1]); o[2]=(short)f2bf(a[2]); o[3]=(short)f2bf(a[3]);
  o[4]=(short)f2bf(b[0]); o[5]=(short)f2bf(b[1]); o[6]=(short)f2bf(b[2]); o[7]=(short)f2bf(b[3]);
  ((s8v*)d)[v] = o;
}

// ---------------- W [k][n] fp32 -> Wt [mat][n][k] bf16 ----------------
__global__ void cvt_w(const float* __restrict__ Wq, const float* __restrict__ Wk,
                      const float* __restrict__ Wv, short* __restrict__ Wt){
  int i = blockIdx.x * 256 + threadIdx.x;          // 0 .. 3*768*768-1
  int mat = i / (ND*ND);
  int rem = i - mat * (ND*ND);
  int k = rem / ND;
  int n = rem - k * ND;
  const float* W = (mat == 0) ? Wq : (mat == 1 ? Wk : Wv);
  Wt[(long)mat*ND*ND + (long)n*ND + k] = (short)f2bf(W[rem]);
}

// ---------------- fused QKV GEMM: 256x256 tile, BK=32, triple-buffered,
// counted vmcnt(4) pipeline, one raw s_barrier per K-step, setprio MFMA,
// LDS-shuffle coalesced epilogue. (unchanged from round 4 — passing) -------
__global__ __launch_bounds__(512, 2)
void qkv_gemm(const short* __restrict__ Xf, const short* __restrict__ Xt,
              const short* __restrict__ Wt,
              const float* __restrict__ bq, const float* __restrict__ bk,
              const float* __restrict__ bv,
              short* __restrict__ Qw, short* __restrict__ Kw, short* __restrict__ Vtw){
  __shared__ short smem[49152];   // 96 KB: A slots @ s*8192, B slots @ 24576 + s*8192

  int bid = blockIdx.x;                       // 1152 blocks, %8==0
  int wg  = (bid & 7) * 144 + (bid >> 3);     // XCD-contiguous chunks
  int mat = wg / 384;
  int r   = wg - mat * 384;
  int mt  = r / 3;
  int nt  = r - mt * 3;                       // nt fastest: neighbors share A-panel

  const short* A  = (mat == 0) ? Xf : Xt;
  const short* Wp = Wt + (long)mat * ND * ND;

  int t_ = threadIdx.x, wv = t_ >> 6, l = t_ & 63, g = l >> 4, c = l & 15;
  int wm = wv >> 2, wn = wv & 3;              // 2M x 4N waves, 128x64 per wave
  int m0 = mt * 256, n0 = nt * 256;

  short* As[3] = { smem, smem + 8192, smem + 16384 };
  short* Bs[3] = { smem + 24576, smem + 32768, smem + 40960 };

  auto stage = [&](int kt, short* Ab, short* Bb, int ci){
    int chunk = ci * 8 + wv;                  // wave-uniform
    int ch = chunk & 15;
    int idx = ch * 64 + l;
    int row = idx >> 2, slot = idx & 3;       // 256 rows x 4 slots of 16B
    int kcol = kt * 32 + ((slot ^ ((row >> 1) & 3)) << 3);
    if (chunk < 16){
      const short* gp = A + (long)(m0 + row) * ND + kcol;
      __builtin_amdgcn_global_load_lds((const GAS unsigned int*)gp,
                                       (LAS unsigned int*)(Ab + ch * 512), 16, 0, 0);
    } else {
      const short* gp = Wp + (long)(n0 + row) * ND + kcol;
      __builtin_amdgcn_global_load_lds((const GAS unsigned int*)gp,
                                       (LAS unsigned int*)(Bb + ch * 512), 16, 0, 0);
    }
  };

  f32x4 zero = {0.f, 0.f, 0.f, 0.f};
  f32x4 acc[8][4];
  #pragma unroll
  for (int i = 0; i < 8; ++i)
    #pragma unroll
    for (int j = 0; j < 4; ++j) acc[i][j] = zero;

  #pragma unroll
  for (int ci = 0; ci < 4; ++ci) stage(0, As[0], Bs[0], ci);
  #pragma unroll
  for (int ci = 0; ci < 4; ++ci) stage(1, As[1], Bs[1], ci);

  auto step = [&](const short* Asl, const short* Bsl, short* An, short* Bn, int t){
    if (t == 23) asm volatile("s_waitcnt vmcnt(0)" ::: "memory");
    else         asm volatile("s_waitcnt vmcnt(4)" ::: "memory");
    __builtin_amdgcn_s_barrier();
    bf16x8 af[8], bfr[4];
    #pragma unroll
    for (int ms = 0; ms < 4; ++ms){
      int row = wm * 128 + ms * 16 + c;
      af[ms] = *(const bf16x8*)(Asl + row * 32 + ((g ^ ((row >> 1) & 3)) << 3));
    }
    if (t < 22) stage(t + 2, An, Bn, 0);
    #pragma unroll
    for (int ns = 0; ns < 4; ++ns){
      int row = wn * 64 + ns * 16 + c;
      bfr[ns] = *(const bf16x8*)(Bsl + row * 32 + ((g ^ ((row >> 1) & 3)) << 3));
    }
    if (t < 22) stage(t + 2, An, Bn, 1);
    #pragma unroll
    for (int ms = 4; ms < 8; ++ms){
      int row = wm * 128 + ms * 16 + c;
      af[ms] = *(const bf16x8*)(Asl + row * 32 + ((g ^ ((row >> 1) & 3)) << 3));
    }
    if (t < 22){ stage(t + 2, An, Bn, 2); stage(t + 2, An, Bn, 3); }
    __builtin_amdgcn_s_setprio(1);
    #pragma unroll
    for (int ms = 0; ms < 8; ++ms)
      #pragma unroll
      for (int ns = 0; ns < 4; ++ns)
        acc[ms][ns] = mfma16(af[ms], bfr[ns], acc[ms][ns]);
    __builtin_amdgcn_s_setprio(0);
  };

  for (int it = 0; it < 8; ++it){
    int t = it * 3;
    step(As[0], Bs[0], As[2], Bs[2], t);
    step(As[1], Bs[1], As[0], Bs[0], t + 1);
    step(As[2], Bs[2], As[1], Bs[1], t + 2);
  }

  __builtin_amdgcn_s_barrier();              // all K-loop LDS reads done everywhere

  // ---- epilogue: wave-private 8KB LDS chunk -> coalesced 16B stores
  int n0g = n0 + wn * 64;                    // 64 cols = exactly one head
  const float* bias = (mat == 0) ? bq : (mat == 1 ? bk : bv);
  float bb[4];
  #pragma unroll
  for (int ns = 0; ns < 4; ++ns) bb[ns] = bias[n0g + ns * 16 + c];
  short* chunk = smem + wv * 4096;           // 8 KB per wave
  int hq = n0g >> 6;

  if (mat < 2){
    short* O = (mat == 0) ? Qw : Kw;
    float scl = (mat == 0) ? QSCALE : 1.0f;
    #pragma unroll
    for (int sp = 0; sp < 2; ++sp){
      #pragma unroll
      for (int msl = 0; msl < 4; ++msl){
        #pragma unroll
        for (int ns = 0; ns < 4; ++ns){
          int col = ns * 16 + c;             // hs
          #pragma unroll
          for (int i = 0; i < 4; ++i){
            int row = msl * 16 + g * 4 + i;  // s-local 0..63
            chunk[row * 64 + (((col >> 3) ^ (row & 7)) << 3) + (col & 7)] =
                (short)f2bf((acc[sp * 4 + msl][ns][i] + bb[ns]) * scl);
          }
        }
      }
      asm volatile("s_waitcnt lgkmcnt(0)" ::: "memory");
      __builtin_amdgcn_sched_barrier(0);
      #pragma unroll
      for (int rr = 0; rr < 8; ++rr){
        int row = rr * 8 + (l >> 3);         // 0..63, all 64 rows covered
        int slot = l & 7;
        bf16x8 v = *(const bf16x8*)(chunk + row * 64 + ((slot ^ (row & 7)) << 3));
        int m = m0 + wm * 128 + sp * 64 + row;
        int b = m >> 9, s2 = m & 511;
        *(bf16x8*)(O + (((long)(b * NH + hq) * NS + s2) << 6) + slot * 8) = v;
      }
      if (sp == 0){ asm volatile("s_waitcnt lgkmcnt(0)" ::: "memory"); }
    }
  } else {
    #pragma unroll
    for (int sp = 0; sp < 2; ++sp){
      #pragma unroll
      for (int msl = 0; msl < 4; ++msl){
        #pragma unroll
        for (int ns = 0; ns < 4; ++ns){
          int hs = ns * 16 + c;              // row 0..63
          #pragma unroll
          for (int i = 0; i < 4; ++i){
            int col = msl * 16 + g * 4 + i;  // s-local 0..63
            chunk[hs * 64 + (((col >> 3) ^ (hs & 7)) << 3) + (col & 7)] =
                (short)f2bf(acc[sp * 4 + msl][ns][i] + bb[ns]);
          }
        }
      }
      asm volatile("s_waitcnt lgkmcnt(0)" ::: "memory");
      __builtin_amdgcn_sched_barrier(0);
      int mbase = m0 + wm * 128 + sp * 64;   // 64-aligned, never crosses b
      int b = mbase >> 9, s0 = mbase & 511;
      #pragma unroll
      for (int rr = 0; rr < 8; ++rr){
        int hs = rr * 8 + (l >> 3);
        int slot = l & 7;
        bf16x8 v = *(const bf16x8*)(chunk + hs * 64 + ((slot ^ (hs & 7)) << 3));
        *(bf16x8*)(Vtw + (long)((b * NH + hq) * 64 + hs) * NS + s0 + slot * 8) = v;
      }
      if (sp == 0){ asm volatile("s_waitcnt lgkmcnt(0)" ::: "memory"); }
    }
  }
}

// ---------------- attention v3: 32x32 MFMA, swapped operands, P in registers.
// One (b,h) per block, 8 waves; each wave: 2 tiles of 32 q-rows, online softmax
// over 16 chunks of 32 keys. q = lane&31 everywhere; P routed via cvt_pk +
// 4 shfl_xor(32) per chunk (no LDS round-trip). ----------------
__global__ __launch_bounds__(512, 1)
void attn_kernel(const short* __restrict__ Qw, const short* __restrict__ Kw,
                 const short* __restrict__ Vtw, float* __restrict__ out){
  extern __shared__ char smem[];
  short* Ks = (short*)smem;              // [512][64] bf16, swizzled rows 128B, 64 KB
  short* Vs = (short*)(smem + 65536);    // [64][512] bf16, swizzled rows 1KB, 64 KB

  int bh = blockIdx.x;                   // 768 blocks
  int t = threadIdx.x, wv = t >> 6, l = t & 63;
  int lam = l & 31, hi = l >> 5;
  int r7 = lam & 7;

  const short* Kb = Kw  + (long)bh * NS * NHS;
  const short* Vb = Vtw + (long)bh * NS * NHS;

  // stage K [key][d] and Vt [d][key] once, 128 chunks of 1KB over 8 waves
  #pragma unroll
  for (int it = 0; it < 8; ++it){
    int chunk = it * 8 + wv;             // wave-uniform, 0..63
    {
      int idx = chunk * 64 + l;
      int row = idx >> 3, slot = idx & 7;
      const short* gk = Kb + row * 64 + ((slot ^ (row & 7)) * 8);
      __builtin_amdgcn_global_load_lds((const GAS unsigned int*)gk,
                                       (LAS unsigned int*)(Ks + chunk * 512), 16, 0, 0);
    }
    {
      int row = chunk, slot = l;         // one chunk = one d-row
      const short* gv = Vb + (long)row * NS + (((slot & 56) | ((slot & 7) ^ (row & 7))) * 8);
      __builtin_amdgcn_global_load_lds((const GAS unsigned int*)gv,
                                       (LAS unsigned int*)(Vs + chunk * 512), 16, 0, 0);
    }
  }
  __syncthreads();

  int b = bh / NH, h = bh - b * NH;
  float* outb = out + (long)b * NS * ND + (long)h * 64;

  for (int qt = 0; qt < 2; ++qt){
    int q0 = wv * 64 + qt * 32;
    // Q as B-operand: B[k=hi*8+j][col=q=lam], d = dk*16 + hi*8 + j
    const short* Qb = Qw + (((long)bh * NS + q0 + lam) << 6) + hi * 8;
    bf16x8 qf[4];
    #pragma unroll
    for (int dk = 0; dk < 4; ++dk) qf[dk] = *(const bf16x8*)(Qb + dk * 16);

    f32x16 o0, o1;                       // O[q=q0+lam][d=(reg&3)+8*(reg>>2)+4*hi+32*dh]
    #pragma unroll
    for (int j = 0; j < 16; ++j){ o0[j] = 0.f; o1[j] = 0.f; }
    float m_run = -1e30f, lsum = 0.f;

    #pragma unroll
    for (int ch = 0; ch < 16; ++ch){
      // ---- QK^T (swapped): s[reg] = S[key=ch*32+(reg&3)+8*(reg>>2)+4*hi][q=q0+lam]
      f32x16 s;
      #pragma unroll
      for (int j = 0; j < 16; ++j) s[j] = 0.f;
      const char* kbase = (const char*)Ks + (ch * 32 + lam) * 128;
      #pragma unroll
      for (int dk = 0; dk < 4; ++dk){
        bf16x8 kf = *(const bf16x8*)(kbase + (((hi + 2 * dk) ^ r7) << 4));
        s = mfma32(kf, qf[dk], s);
      }

      // ---- online softmax (defer-max, THR=8), per-lane q = lam
      float t8[8], t4[4];
      #pragma unroll
      for (int j = 0; j < 8; ++j) t8[j] = fmaxf(s[j], s[j + 8]);
      #pragma unroll
      for (int j = 0; j < 4; ++j) t4[j] = fmaxf(t8[j], t8[j + 4]);
      float m1 = fmaxf(fmaxf(t4[0], t4[1]), fmaxf(t4[2], t4[3]));
      float pmax = fmaxf(m1, __shfl_xor(m1, 32));
      if (__any(pmax > m_run + 8.0f)){
        float mnew = fmaxf(m_run, pmax);
        float cf = exp2f(m_run - mnew);
        lsum *= cf;
        #pragma unroll
        for (int j = 0; j < 16; ++j){ o0[j] *= cf; o1[j] *= cf; }
        m_run = mnew;
      }
      float p[16];
      #pragma unroll
      for (int j = 0; j < 16; ++j) p[j] = exp2f(s[j] - m_run);
      float a8[8], a4[4];
      #pragma unroll
      for (int j = 0; j < 8; ++j) a8[j] = p[j] + p[j + 8];
      #pragma unroll
      for (int j = 0; j < 4; ++j) a4[j] = a8[j] + a8[j + 4];
      lsum += (a4[0] + a4[1]) + (a4[2] + a4[3]);

      // ---- P -> bf16 fragments, single-partner exchange (lane ^ 32)
      // w[rr] = keys {K(rr)+4hi, +1}, K = [0,2,8,10,16,18,24,26]
      unsigned int w[8];
      #pragma unroll
      for (int rr = 0; rr < 8; ++rr) w[rr] = cvtpk(p[2 * rr], p[2 * rr + 1]);
      unsigned int y0 = (unsigned int)__shfl_xor((int)(hi ? w[0] : w[2]), 32);
      unsigned int y1 = (unsigned int)__shfl_xor((int)(hi ? w[1] : w[3]), 32);
      unsigned int y2 = (unsigned int)__shfl_xor((int)(hi ? w[4] : w[6]), 32);
      unsigned int y3 = (unsigned int)__shfl_xor((int)(hi ? w[5] : w[7]), 32);
      u32x4 fa, fb;
      if (hi){
        fa[0] = y0;   fa[1] = y1;   fa[2] = w[2]; fa[3] = w[3];   // keys 8..15
        fb[0] = y2;   fb[1] = y3;   fb[2] = w[6]; fb[3] = w[7];   // keys 24..31
      } else {
        fa[0] = w[0]; fa[1] = w[1]; fa[2] = y0;   fa[3] = y1;     // keys 0..7
        fb[0] = w[4]; fb[1] = w[5]; fb[2] = y2;   fb[3] = y3;     // keys 16..23
      }
      bf16x8 pa = u2b(fa), pb = u2b(fb);

      // ---- PV (swapped): o[dh] += mfma32(V^T-frag, P-frag)
      const char* vb0 = (const char*)Vs + lam * 1024;          // d = lam
      const char* vb1 = (const char*)Vs + (32 + lam) * 1024;   // d = 32+lam
      int sl0 = ch * 4 + hi, sl1 = ch * 4 + 2 + hi;
      int sw0 = ((sl0 & 56) | ((sl0 & 7) ^ r7)) << 4;
      int sw1 = ((sl1 & 56) | ((sl1 & 7) ^ r7)) << 4;
      bf16x8 v00 = *(const bf16x8*)(vb0 + sw0);
      bf16x8 v01 = *(const bf16x8*)(vb0 + sw1);
      bf16x8 v10 = *(const bf16x8*)(vb1 + sw0);
      bf16x8 v11 = *(const bf16x8*)(vb1 + sw1);
      o0 = mfma32(v00, pa, o0);
      o0 = mfma32(v01, pb, o0);
      o1 = mfma32(v10, pa, o1);
      o1 = mfma32(v11, pb, o1);
    }

    // ---- epilogue: combine l across partner, deferred 1/sum, float4 stores
    float lt = lsum + __shfl_xor(lsum, 32);
    float invl = 1.0f / lt;
    float* orow = outb + (long)(q0 + lam) * ND;
    #pragma unroll
    for (int r = 0; r < 4; ++r){
      f4 u0, u1;
      #pragma unroll
      for (int jj = 0; jj < 4; ++jj){
        u0[jj] = o0[4 * r + jj] * invl;
        u1[jj] = o1[4 * r + jj] * invl;
      }
      *(f4*)(orow + 4 * hi + 8 * r)      = u0;   // d = 4hi+8r+{0..3}
      *(f4*)(orow + 32 + 4 * hi + 8 * r) = u1;   // d = 32+4hi+8r+{0..3}
    }
  }
}

// ---------------- launch ----------------
extern "C" void kernel_launch(void* const* d_in, const int* in_sizes, int n_in,
                              void* d_out, int out_size, void* d_ws, size_t ws_size,
                              hipStream_t stream){
  const float* from_t = (const float*)d_in[0];
  const float* to_t   = (const float*)d_in[1];
  const float* Wq = (const float*)d_in[2];
  const float* bq = (const float*)d_in[3];
  const float* Wk = (const float*)d_in[4];
  const float* bk = (const float*)d_in[5];
  const float* Wv = (const float*)d_in[6];
  const float* bv = (const float*)d_in[7];

  short* fb  = (short*)d_ws;                 // 25165824 bf16
  short* tb  = fb  + 25165824;               // 25165824
  short* Wt  = tb  + 25165824;               // 1769472
  short* Qw  = Wt  + 1769472;                // 25165824
  short* Kw  = Qw  + 25165824;               // 25165824
  short* Vtw = Kw  + 25165824;               // 25165824  (total ~243 MB)

  cvt_x<<<24576, 256, 0, stream>>>(from_t, to_t, fb, tb);
  cvt_w<<<6912, 256, 0, stream>>>(Wq, Wk, Wv, Wt);
  qkv_gemm<<<1152, 512, 0, stream>>>(fb, tb, Wt, bq, bk, bv, Qw, Kw, Vtw);
  attn_kernel<<<768, 512, 131072, stream>>>(Qw, Kw, Vtw, (float*)d_out);
}

// Round 6
// 330.172 us; speedup vs baseline: 1.4444x; 1.0024x over previous
//
#include <hip/hip_runtime.h>
#include <hip/hip_bf16.h>

#define GAS __attribute__((address_space(1)))
#define LAS __attribute__((address_space(3)))

typedef __attribute__((ext_vector_type(8))) short   bf16x8;
typedef __attribute__((ext_vector_type(4))) float   f32x4;
typedef __attribute__((ext_vector_type(16))) float  f32x16;
typedef __attribute__((ext_vector_type(4))) float   f4;
typedef __attribute__((ext_vector_type(8))) short   s8v;
typedef __attribute__((ext_vector_type(2))) unsigned int u32x2;
typedef __attribute__((ext_vector_type(4))) unsigned int u32x4;

#define NB  64
#define NS  512
#define ND  768
#define NH  12
#define NHS 64
#define NM  (NB*NS)    /* 32768 */
#define NBH (NB*NH)    /* 768   */

// 0.125 * log2(e): folded into Q so softmax uses exp2 directly
#define QSCALE 0.18033688011112042f

__device__ __forceinline__ unsigned short f2bf(float x){
  unsigned int u = __float_as_uint(x);
  u += 0x7fffu + ((u >> 16) & 1u);       // round-to-nearest-even
  return (unsigned short)(u >> 16);
}

__device__ __forceinline__ f32x4 mfma16(bf16x8 a, bf16x8 b, f32x4 c){
  return __builtin_amdgcn_mfma_f32_16x16x32_bf16(a, b, c, 0, 0, 0);
}

__device__ __forceinline__ f32x16 mfma32(bf16x8 a, bf16x8 b, f32x16 c){
  return __builtin_amdgcn_mfma_f32_32x32x16_bf16(a, b, c, 0, 0, 0);
}

__device__ __forceinline__ unsigned int cvtpk(float lo, float hi){
  unsigned int r;
  asm("v_cvt_pk_bf16_f32 %0, %1, %2" : "=v"(r) : "v"(lo), "v"(hi));
  return r;
}

__device__ __forceinline__ bf16x8 u2b(u32x4 u){
  union { u32x4 a; bf16x8 b; } c; c.a = u; return c.b;
}

// ---------------- fp32 -> bf16 convert of activations ----------------
__global__ void cvt_x(const float* __restrict__ from_t, const float* __restrict__ to_t,
                      short* __restrict__ fb, short* __restrict__ tb){
  int v = blockIdx.x * 256 + threadIdx.x;          // one thread = 8 elems
  const int NG = NM * ND / 8;                      // 3145728 per tensor
  const float* s; short* d;
  if (v < NG){ s = from_t; d = fb; } else { s = to_t; d = tb; v -= NG; }
  f4 a = ((const f4*)s)[(long)v * 2];
  f4 b = ((const f4*)s)[(long)v * 2 + 1];
  s8v o;
  o[0]=(short)f2bf(a[0]); o[1]=(short)f2bf(a[1]); o[2]=(short)f2bf(a[2]); o[3]=(short)f2bf(a[3]);
  o[4]=(short)f2bf(b[0]); o[5]=(short)f2bf(b[1]); o[6]=(short)f2bf(b[2]); o[7]=(short)f2bf(b[3]);
  ((s8v*)d)[v] = o;
}

// ---------------- W [k][n] fp32 -> Wt [mat][n][k] bf16 ----------------
__global__ void cvt_w(const float* __restrict__ Wq, const float* __restrict__ Wk,
                      const float* __restrict__ Wv, short* __restrict__ Wt){
  int i = blockIdx.x * 256 + threadIdx.x;          // 0 .. 3*768*768-1
  int mat = i / (ND*ND);
  int rem = i - mat * (ND*ND);
  int k = rem / ND;
  int n = rem - k * ND;
  const float* W = (mat == 0) ? Wq : (mat == 1 ? Wk : Wv);
  Wt[(long)mat*ND*ND + (long)n*ND + k] = (short)f2bf(W[rem]);
}

// ---------------- fused QKV GEMM v3: 256x256 tile, BK=32, 4-slot LDS ring,
// 2 phases per K-tile {dsr, stage, bar, lgkm0, 16 MFMA, bar}, counted vmcnt(8)
// placed before the tile-boundary barrier (lookahead = 3 K-tiles). ----------
__global__ __launch_bounds__(512, 2)
void qkv_gemm(const short* __restrict__ Xf, const short* __restrict__ Xt,
              const short* __restrict__ Wt,
              const float* __restrict__ bq, const float* __restrict__ bk,
              const float* __restrict__ bv,
              short* __restrict__ Qw, short* __restrict__ Kw, short* __restrict__ Vtw){
  __shared__ short smem[65536];   // 128 KB: A slots @ s*8192, B slots @ 32768 + s*8192

  int bid = blockIdx.x;                       // 1152 blocks, %8==0
  int wg  = (bid & 7) * 144 + (bid >> 3);     // XCD-contiguous chunks
  int mat = wg / 384;
  int r   = wg - mat * 384;
  int mt  = r / 3;
  int nt  = r - mt * 3;                       // nt fastest: neighbors share A-panel

  const short* A  = (mat == 0) ? Xf : Xt;
  const short* Wp = Wt + (long)mat * ND * ND;

  int t_ = threadIdx.x, wv = t_ >> 6, l = t_ & 63, g = l >> 4, c = l & 15;
  int wm = wv >> 2, wn = wv & 3;              // 2M x 4N waves, 128x64 per wave
  int m0 = mt * 256, n0 = nt * 256;

  // stage one half (hf: 0=A, 1=B) of K-tile kt2 into ring slot kt2&3.
  // 2 x global_load_lds (16B) per thread; linear LDS dest + inverse-swizzled src.
  auto stageH = [&](int kt2, int hf){
    int sl = kt2 & 3;
    short* base = smem + (hf ? 32768 : 0) + sl * 8192;
    const short* src = hf ? Wp : A;
    int r0 = hf ? n0 : m0;
    #pragma unroll
    for (int j = 0; j < 2; ++j){
      int idx = j * 512 + t_;                 // 0..1023
      int row = idx >> 2, slot = idx & 3;     // 256 rows x 4 slots of 16B
      const short* gp = src + (long)(r0 + row) * ND + kt2 * 32 + ((slot ^ ((row >> 1) & 3)) << 3);
      __builtin_amdgcn_global_load_lds((const GAS unsigned int*)gp,
                                       (LAS unsigned int*)(base + idx * 8), 16, 0, 0);
    }
  };

  f32x4 zero = {0.f, 0.f, 0.f, 0.f};
  f32x4 acc[8][4];
  #pragma unroll
  for (int i = 0; i < 8; ++i)
    #pragma unroll
    for (int j = 0; j < 4; ++j) acc[i][j] = zero;

  // prologue: tiles 0,1,2 in flight (12 loads/thread); own tile-0 drained + barrier
  stageH(0, 0); stageH(0, 1);
  stageH(1, 0); stageH(1, 1);
  stageH(2, 0); stageH(2, 1);
  asm volatile("s_waitcnt vmcnt(8)" ::: "memory");
  __builtin_amdgcn_s_barrier();

  bf16x8 bfr[4];
  for (int kt = 0; kt < 24; ++kt){
    int sl = kt & 3;
    const short* Asl = smem + sl * 8192;
    const short* Bsl = smem + 32768 + sl * 8192;

    // ---- phase A (M-frags 0..3): 8 ds_read + stage A-half of kt+3
    bf16x8 af[4];
    #pragma unroll
    for (int i = 0; i < 4; ++i){
      int row = wm * 128 + i * 16 + c;
      af[i] = *(const bf16x8*)(Asl + row * 32 + ((g ^ ((row >> 1) & 3)) << 3));
    }
    #pragma unroll
    for (int ns = 0; ns < 4; ++ns){
      int row = wn * 64 + ns * 16 + c;
      bfr[ns] = *(const bf16x8*)(Bsl + row * 32 + ((g ^ ((row >> 1) & 3)) << 3));
    }
    if (kt < 21) stageH(kt + 3, 0);
    __builtin_amdgcn_s_barrier();
    asm volatile("s_waitcnt lgkmcnt(0)" ::: "memory");
    __builtin_amdgcn_sched_barrier(0);
    __builtin_amdgcn_s_setprio(1);
    #pragma unroll
    for (int i = 0; i < 4; ++i)
      #pragma unroll
      for (int ns = 0; ns < 4; ++ns)
        acc[i][ns] = mfma16(af[i], bfr[ns], acc[i][ns]);
    __builtin_amdgcn_s_setprio(0);
    __builtin_amdgcn_s_barrier();

    // ---- phase B (M-frags 4..7): 4 ds_read + stage B-half of kt+3
    #pragma unroll
    for (int i = 0; i < 4; ++i){
      int row = wm * 128 + (4 + i) * 16 + c;
      af[i] = *(const bf16x8*)(Asl + row * 32 + ((g ^ ((row >> 1) & 3)) << 3));
    }
    if (kt < 21) stageH(kt + 3, 1);
    __builtin_amdgcn_s_barrier();
    asm volatile("s_waitcnt lgkmcnt(0)" ::: "memory");
    __builtin_amdgcn_sched_barrier(0);
    __builtin_amdgcn_s_setprio(1);
    #pragma unroll
    for (int i = 0; i < 4; ++i)
      #pragma unroll
      for (int ns = 0; ns < 4; ++ns)
        acc[4 + i][ns] = mfma16(af[i], bfr[ns], acc[4 + i][ns]);
    __builtin_amdgcn_s_setprio(0);
    // tile-boundary drain (per-wave) BEFORE the barrier so the barrier
    // publishes "tile kt+1 landed" to all waves. Never 0 until the tail.
    if (kt <= 20)      asm volatile("s_waitcnt vmcnt(8)" ::: "memory");
    else if (kt == 21) asm volatile("s_waitcnt vmcnt(4)" ::: "memory");
    else if (kt == 22) asm volatile("s_waitcnt vmcnt(0)" ::: "memory");
    __builtin_amdgcn_s_barrier();
  }

  // ---- epilogue: wave-private 8KB LDS chunk -> coalesced 16B stores
  int n0g = n0 + wn * 64;                    // 64 cols = exactly one head
  const float* bias = (mat == 0) ? bq : (mat == 1 ? bk : bv);
  float bb[4];
  #pragma unroll
  for (int ns = 0; ns < 4; ++ns) bb[ns] = bias[n0g + ns * 16 + c];
  short* chunk = smem + wv * 4096;           // 8 KB per wave
  int hq = n0g >> 6;

  if (mat < 2){
    short* O = (mat == 0) ? Qw : Kw;
    float scl = (mat == 0) ? QSCALE : 1.0f;
    #pragma unroll
    for (int sp = 0; sp < 2; ++sp){
      #pragma unroll
      for (int msl = 0; msl < 4; ++msl){
        #pragma unroll
        for (int ns = 0; ns < 4; ++ns){
          int col = ns * 16 + c;             // hs
          #pragma unroll
          for (int i = 0; i < 4; ++i){
            int row = msl * 16 + g * 4 + i;  // s-local 0..63
            chunk[row * 64 + (((col >> 3) ^ (row & 7)) << 3) + (col & 7)] =
                (short)f2bf((acc[sp * 4 + msl][ns][i] + bb[ns]) * scl);
          }
        }
      }
      asm volatile("s_waitcnt lgkmcnt(0)" ::: "memory");
      __builtin_amdgcn_sched_barrier(0);
      #pragma unroll
      for (int rr = 0; rr < 8; ++rr){
        int row = rr * 8 + (l >> 3);         // 0..63, all 64 rows covered
        int slot = l & 7;
        bf16x8 v = *(const bf16x8*)(chunk + row * 64 + ((slot ^ (row & 7)) << 3));
        int m = m0 + wm * 128 + sp * 64 + row;
        int b = m >> 9, s2 = m & 511;
        *(bf16x8*)(O + (((long)(b * NH + hq) * NS + s2) << 6) + slot * 8) = v;
      }
      if (sp == 0){ asm volatile("s_waitcnt lgkmcnt(0)" ::: "memory"); }
    }
  } else {
    #pragma unroll
    for (int sp = 0; sp < 2; ++sp){
      #pragma unroll
      for (int msl = 0; msl < 4; ++msl){
        #pragma unroll
        for (int ns = 0; ns < 4; ++ns){
          int hs = ns * 16 + c;              // row 0..63
          #pragma unroll
          for (int i = 0; i < 4; ++i){
            int col = msl * 16 + g * 4 + i;  // s-local 0..63
            chunk[hs * 64 + (((col >> 3) ^ (hs & 7)) << 3) + (col & 7)] =
                (short)f2bf(acc[sp * 4 + msl][ns][i] + bb[ns]);
          }
        }
      }
      asm volatile("s_waitcnt lgkmcnt(0)" ::: "memory");
      __builtin_amdgcn_sched_barrier(0);
      int mbase = m0 + wm * 128 + sp * 64;   // 64-aligned, never crosses b
      int b = mbase >> 9, s0 = mbase & 511;
      #pragma unroll
      for (int rr = 0; rr < 8; ++rr){
        int hs = rr * 8 + (l >> 3);
        int slot = l & 7;
        bf16x8 v = *(const bf16x8*)(chunk + hs * 64 + ((slot ^ (hs & 7)) << 3));
        *(bf16x8*)(Vtw + (long)((b * NH + hq) * 64 + hs) * NS + s0 + slot * 8) = v;
      }
      if (sp == 0){ asm volatile("s_waitcnt lgkmcnt(0)" ::: "memory"); }
    }
  }
}

// ---------------- attention v3: 32x32 MFMA, swapped operands, P in registers.
// One (b,h) per block, 8 waves; each wave: 2 tiles of 32 q-rows, online softmax
// over 16 chunks of 32 keys. q = lane&31 everywhere; P routed via cvt_pk +
// 4 shfl_xor(32) per chunk (no LDS round-trip). (unchanged — passing) --------
__global__ __launch_bounds__(512, 1)
void attn_kernel(const short* __restrict__ Qw, const short* __restrict__ Kw,
                 const short* __restrict__ Vtw, float* __restrict__ out){
  extern __shared__ char smem[];
  short* Ks = (short*)smem;              // [512][64] bf16, swizzled rows 128B, 64 KB
  short* Vs = (short*)(smem + 65536);    // [64][512] bf16, swizzled rows 1KB, 64 KB

  int bh = blockIdx.x;                   // 768 blocks
  int t = threadIdx.x, wv = t >> 6, l = t & 63;
  int lam = l & 31, hi = l >> 5;
  int r7 = lam & 7;

  const short* Kb = Kw  + (long)bh * NS * NHS;
  const short* Vb = Vtw + (long)bh * NS * NHS;

  // stage K [key][d] and Vt [d][key] once, 128 chunks of 1KB over 8 waves
  #pragma unroll
  for (int it = 0; it < 8; ++it){
    int chunk = it * 8 + wv;             // wave-uniform, 0..63
    {
      int idx = chunk * 64 + l;
      int row = idx >> 3, slot = idx & 7;
      const short* gk = Kb + row * 64 + ((slot ^ (row & 7)) * 8);
      __builtin_amdgcn_global_load_lds((const GAS unsigned int*)gk,
                                       (LAS unsigned int*)(Ks + chunk * 512), 16, 0, 0);
    }
    {
      int row = chunk, slot = l;         // one chunk = one d-row
      const short* gv = Vb + (long)row * NS + (((slot & 56) | ((slot & 7) ^ (row & 7))) * 8);
      __builtin_amdgcn_global_load_lds((const GAS unsigned int*)gv,
                                       (LAS unsigned int*)(Vs + chunk * 512), 16, 0, 0);
    }
  }
  __syncthreads();

  int b = bh / NH, h = bh - b * NH;
  float* outb = out + (long)b * NS * ND + (long)h * 64;

  for (int qt = 0; qt < 2; ++qt){
    int q0 = wv * 64 + qt * 32;
    // Q as B-operand: B[k=hi*8+j][col=q=lam], d = dk*16 + hi*8 + j
    const short* Qb = Qw + (((long)bh * NS + q0 + lam) << 6) + hi * 8;
    bf16x8 qf[4];
    #pragma unroll
    for (int dk = 0; dk < 4; ++dk) qf[dk] = *(const bf16x8*)(Qb + dk * 16);

    f32x16 o0, o1;                       // O[q=q0+lam][d=(reg&3)+8*(reg>>2)+4*hi+32*dh]
    #pragma unroll
    for (int j = 0; j < 16; ++j){ o0[j] = 0.f; o1[j] = 0.f; }
    float m_run = -1e30f, lsum = 0.f;

    #pragma unroll
    for (int ch = 0; ch < 16; ++ch){
      // ---- QK^T (swapped): s[reg] = S[key=ch*32+(reg&3)+8*(reg>>2)+4*hi][q=q0+lam]
      f32x16 s;
      #pragma unroll
      for (int j = 0; j < 16; ++j) s[j] = 0.f;
      const char* kbase = (const char*)Ks + (ch * 32 + lam) * 128;
      #pragma unroll
      for (int dk = 0; dk < 4; ++dk){
        bf16x8 kf = *(const bf16x8*)(kbase + (((hi + 2 * dk) ^ r7) << 4));
        s = mfma32(kf, qf[dk], s);
      }

      // ---- online softmax (defer-max, THR=8), per-lane q = lam
      float t8[8], t4[4];
      #pragma unroll
      for (int j = 0; j < 8; ++j) t8[j] = fmaxf(s[j], s[j + 8]);
      #pragma unroll
      for (int j = 0; j < 4; ++j) t4[j] = fmaxf(t8[j], t8[j + 4]);
      float m1 = fmaxf(fmaxf(t4[0], t4[1]), fmaxf(t4[2], t4[3]));
      float pmax = fmaxf(m1, __shfl_xor(m1, 32));
      if (__any(pmax > m_run + 8.0f)){
        float mnew = fmaxf(m_run, pmax);
        float cf = exp2f(m_run - mnew);
        lsum *= cf;
        #pragma unroll
        for (int j = 0; j < 16; ++j){ o0[j] *= cf; o1[j] *= cf; }
        m_run = mnew;
      }
      float p[16];
      #pragma unroll
      for (int j = 0; j < 16; ++j) p[j] = exp2f(s[j] - m_run);
      float a8[8], a4[4];
      #pragma unroll
      for (int j = 0; j < 8; ++j) a8[j] = p[j] + p[j + 8];
      #pragma unroll
      for (int j = 0; j < 4; ++j) a4[j] = a8[j] + a8[j + 4];
      lsum += (a4[0] + a4[1]) + (a4[2] + a4[3]);

      // ---- P -> bf16 fragments, single-partner exchange (lane ^ 32)
      unsigned int w[8];
      #pragma unroll
      for (int rr = 0; rr < 8; ++rr) w[rr] = cvtpk(p[2 * rr], p[2 * rr + 1]);
      unsigned int y0 = (unsigned int)__shfl_xor((int)(hi ? w[0] : w[2]), 32);
      unsigned int y1 = (unsigned int)__shfl_xor((int)(hi ? w[1] : w[3]), 32);
      unsigned int y2 = (unsigned int)__shfl_xor((int)(hi ? w[4] : w[6]), 32);
      unsigned int y3 = (unsigned int)__shfl_xor((int)(hi ? w[5] : w[7]), 32);
      u32x4 fa, fb;
      if (hi){
        fa[0] = y0;   fa[1] = y1;   fa[2] = w[2]; fa[3] = w[3];   // keys 8..15
        fb[0] = y2;   fb[1] = y3;   fb[2] = w[6]; fb[3] = w[7];   // keys 24..31
      } else {
        fa[0] = w[0]; fa[1] = w[1]; fa[2] = y0;   fa[3] = y1;     // keys 0..7
        fb[0] = w[4]; fb[1] = w[5]; fb[2] = y2;   fb[3] = y3;     // keys 16..23
      }
      bf16x8 pa = u2b(fa), pb = u2b(fb);

      // ---- PV (swapped): o[dh] += mfma32(V^T-frag, P-frag)
      const char* vb0 = (const char*)Vs + lam * 1024;          // d = lam
      const char* vb1 = (const char*)Vs + (32 + lam) * 1024;   // d = 32+lam
      int sl0 = ch * 4 + hi, sl1 = ch * 4 + 2 + hi;
      int sw0 = ((sl0 & 56) | ((sl0 & 7) ^ r7)) << 4;
      int sw1 = ((sl1 & 56) | ((sl1 & 7) ^ r7)) << 4;
      bf16x8 v00 = *(const bf16x8*)(vb0 + sw0);
      bf16x8 v01 = *(const bf16x8*)(vb0 + sw1);
      bf16x8 v10 = *(const bf16x8*)(vb1 + sw0);
      bf16x8 v11 = *(const bf16x8*)(vb1 + sw1);
      o0 = mfma32(v00, pa, o0);
      o0 = mfma32(v01, pb, o0);
      o1 = mfma32(v10, pa, o1);
      o1 = mfma32(v11, pb, o1);
    }

    // ---- epilogue: combine l across partner, deferred 1/sum, float4 stores
    float lt = lsum + __shfl_xor(lsum, 32);
    float invl = 1.0f / lt;
    float* orow = outb + (long)(q0 + lam) * ND;
    #pragma unroll
    for (int r = 0; r < 4; ++r){
      f4 u0, u1;
      #pragma unroll
      for (int jj = 0; jj < 4; ++jj){
        u0[jj] = o0[4 * r + jj] * invl;
        u1[jj] = o1[4 * r + jj] * invl;
      }
      *(f4*)(orow + 4 * hi + 8 * r)      = u0;   // d = 4hi+8r+{0..3}
      *(f4*)(orow + 32 + 4 * hi + 8 * r) = u1;   // d = 32+4hi+8r+{0..3}
    }
  }
}

// ---------------- launch ----------------
extern "C" void kernel_launch(void* const* d_in, const int* in_sizes, int n_in,
                              void* d_out, int out_size, void* d_ws, size_t ws_size,
                              hipStream_t stream){
  const float* from_t = (const float*)d_in[0];
  const float* to_t   = (const float*)d_in[1];
  const float* Wq = (const float*)d_in[2];
  const float* bq = (const float*)d_in[3];
  const float* Wk = (const float*)d_in[4];
  const float* bk = (const float*)d_in[5];
  const float* Wv = (const float*)d_in[6];
  const float* bv = (const float*)d_in[7];

  short* fb  = (short*)d_ws;                 // 25165824 bf16
  short* tb  = fb  + 25165824;               // 25165824
  short* Wt  = tb  + 25165824;               // 1769472
  short* Qw  = Wt  + 1769472;                // 25165824
  short* Kw  = Qw  + 25165824;               // 25165824
  short* Vtw = Kw  + 25165824;               // 25165824  (total ~243 MB)

  cvt_x<<<24576, 256, 0, stream>>>(from_t, to_t, fb, tb);
  cvt_w<<<6912, 256, 0, stream>>>(Wq, Wk, Wv, Wt);
  qkv_gemm<<<1152, 512, 0, stream>>>(fb, tb, Wt, bq, bk, bv, Qw, Kw, Vtw);
  attn_kernel<<<768, 512, 131072, stream>>>(Qw, Kw, Vtw, (float*)d_out);
}

// Round 7
// 312.206 us; speedup vs baseline: 1.5275x; 1.0575x over previous
//
#include <hip/hip_runtime.h>
#include <hip/hip_bf16.h>

#define GAS __attribute__((address_space(1)))
#define LAS __attribute__((address_space(3)))

typedef __attribute__((ext_vector_type(8))) short   bf16x8;
typedef __attribute__((ext_vector_type(4))) float   f32x4;
typedef __attribute__((ext_vector_type(16))) float  f32x16;
typedef __attribute__((ext_vector_type(4))) float   f4;
typedef __attribute__((ext_vector_type(8))) short   s8v;
typedef __attribute__((ext_vector_type(2))) unsigned int u32x2;
typedef __attribute__((ext_vector_type(4))) unsigned int u32x4;

#define NB  64
#define NS  512
#define ND  768
#define NH  12
#define NHS 64
#define NM  (NB*NS)    /* 32768 */
#define NBH (NB*NH)    /* 768   */

// 0.125 * log2(e): folded into Q so softmax uses exp2 directly
#define QSCALE 0.18033688011112042f

__device__ __forceinline__ unsigned short f2bf(float x){
  unsigned int u = __float_as_uint(x);
  u += 0x7fffu + ((u >> 16) & 1u);       // round-to-nearest-even
  return (unsigned short)(u >> 16);
}

__device__ __forceinline__ f32x4 mfma16(bf16x8 a, bf16x8 b, f32x4 c){
  return __builtin_amdgcn_mfma_f32_16x16x32_bf16(a, b, c, 0, 0, 0);
}

__device__ __forceinline__ f32x16 mfma32(bf16x8 a, bf16x8 b, f32x16 c){
  return __builtin_amdgcn_mfma_f32_32x32x16_bf16(a, b, c, 0, 0, 0);
}

__device__ __forceinline__ unsigned int cvtpk(float lo, float hi){
  unsigned int r;
  asm("v_cvt_pk_bf16_f32 %0, %1, %2" : "=v"(r) : "v"(lo), "v"(hi));
  return r;
}

__device__ __forceinline__ bf16x8 u2b(u32x4 u){
  union { u32x4 a; bf16x8 b; } c; c.a = u; return c.b;
}

// ---------------- W [k][n] fp32 -> Wt [mat][n][k] bf16 ----------------
__global__ void cvt_w(const float* __restrict__ Wq, const float* __restrict__ Wk,
                      const float* __restrict__ Wv, short* __restrict__ Wt){
  int i = blockIdx.x * 256 + threadIdx.x;          // 0 .. 3*768*768-1
  int mat = i / (ND*ND);
  int rem = i - mat * (ND*ND);
  int k = rem / ND;
  int n = rem - k * ND;
  const float* W = (mat == 0) ? Wq : (mat == 1 ? Wk : Wv);
  Wt[(long)mat*ND*ND + (long)n*ND + k] = (short)f2bf(W[rem]);
}

// ---------------- fused QKV GEMM v4: cvt_x fused in. A read as fp32 from the
// original activations (reg-staged: load in phase-A of kt for kt+3, cvt_pk +
// ds_write in phase-A of kt+1); B via global_load_lds. 4-slot LDS ring, BK=32,
// counted vmcnt(8). ----------
__global__ __launch_bounds__(512, 2)
void qkv_gemm(const float* __restrict__ from_t, const float* __restrict__ to_t,
              const short* __restrict__ Wt,
              const float* __restrict__ bq, const float* __restrict__ bk,
              const float* __restrict__ bv,
              short* __restrict__ Qw, short* __restrict__ Kw, short* __restrict__ Vtw){
  __shared__ short smem[65536];   // 128 KB: A slots @ s*8192, B slots @ 32768 + s*8192

  int bid = blockIdx.x;                       // 1152 blocks, %8==0
  int wg  = (bid & 7) * 144 + (bid >> 3);     // XCD-contiguous chunks
  int mat = wg / 384;
  int r   = wg - mat * 384;
  int mt  = r / 3;
  int nt  = r - mt * 3;                       // nt fastest: neighbors share A-panel

  const float* Af = (mat == 0) ? from_t : to_t;
  const short* Wp = Wt + (long)mat * ND * ND;

  int t_ = threadIdx.x, wv = t_ >> 6, l = t_ & 63, g = l >> 4, c = l & 15;
  int wm = wv >> 2, wn = wv & 3;              // 2M x 4N waves, 128x64 per wave
  int m0 = mt * 256, n0 = nt * 256;

  f4 areg[4];                                 // in-flight A tile (fp32), 16 VGPR

  // issue 4 x dwordx4 fp32 loads for A-tile kt2 (linear, coalesced)
  auto stageA_load = [&](int kt2){
    #pragma unroll
    for (int j = 0; j < 2; ++j){
      int idx = j * 512 + t_;                 // 0..1023
      int row = idx >> 2, slot = idx & 3;     // 256 rows x 4 slots (8 fp32 each)
      const float* gp = Af + (long)(m0 + row) * ND + kt2 * 32 + slot * 8;
      areg[j * 2]     = *(const f4*)(gp);
      areg[j * 2 + 1] = *(const f4*)(gp + 4);
    }
  };
  // cvt_pk + swizzled ds_write_b128 of the held A tile into ring slot kt2&3
  auto stageA_write = [&](int kt2){
    short* base = smem + (kt2 & 3) * 8192;
    #pragma unroll
    for (int j = 0; j < 2; ++j){
      int idx = j * 512 + t_;
      int row = idx >> 2, slot = idx & 3;
      int sw = slot ^ ((row >> 1) & 3);       // swizzled write (read side XORs same)
      u32x4 pk;
      pk[0] = cvtpk(areg[j * 2][0],     areg[j * 2][1]);
      pk[1] = cvtpk(areg[j * 2][2],     areg[j * 2][3]);
      pk[2] = cvtpk(areg[j * 2 + 1][0], areg[j * 2 + 1][1]);
      pk[3] = cvtpk(areg[j * 2 + 1][2], areg[j * 2 + 1][3]);
      *(bf16x8*)(base + row * 32 + sw * 8) = u2b(pk);
    }
  };
  // B half-tile via global_load_lds (linear dest + inverse-swizzled source)
  auto stageB = [&](int kt2){
    short* base = smem + 32768 + (kt2 & 3) * 8192;
    #pragma unroll
    for (int j = 0; j < 2; ++j){
      int idx = j * 512 + t_;
      int row = idx >> 2, slot = idx & 3;
      const short* gp = Wp + (long)(n0 + row) * ND + kt2 * 32 + ((slot ^ ((row >> 1) & 3)) << 3);
      __builtin_amdgcn_global_load_lds((const GAS unsigned int*)gp,
                                       (LAS unsigned int*)(base + idx * 8), 16, 0, 0);
    }
  };

  f32x4 zero = {0.f, 0.f, 0.f, 0.f};
  f32x4 acc[8][4];
  #pragma unroll
  for (int i = 0; i < 8; ++i)
    #pragma unroll
    for (int j = 0; j < 4; ++j) acc[i][j] = zero;

  // prologue: B tiles 0,1,2 in flight; A tiles 0,1 written; A tile 2 in regs
  stageB(0);
  stageA_load(0);
  stageA_write(0);                            // compiler vmcnt-waits A0 (once)
  stageA_load(1);
  stageA_write(1);
  stageA_load(2);                             // held for kt=0's write
  stageB(1); stageB(2);
  asm volatile("s_waitcnt vmcnt(8)" ::: "memory");   // B(0) landed
  asm volatile("s_waitcnt lgkmcnt(0)" ::: "memory"); // A-writes drained
  __builtin_amdgcn_s_barrier();

  bf16x8 bfr[4];
  for (int kt = 0; kt < 24; ++kt){
    int sl = kt & 3;
    const short* Asl = smem + sl * 8192;
    const short* Bsl = smem + 32768 + sl * 8192;

    // ---- phase A (M-frags 0..3): 8 ds_read; write A(kt+2); issue A-loads(kt+3)
    bf16x8 af[4];
    #pragma unroll
    for (int i = 0; i < 4; ++i){
      int row = wm * 128 + i * 16 + c;
      af[i] = *(const bf16x8*)(Asl + row * 32 + ((g ^ ((row >> 1) & 3)) << 3));
    }
    #pragma unroll
    for (int ns = 0; ns < 4; ++ns){
      int row = wn * 64 + ns * 16 + c;
      bfr[ns] = *(const bf16x8*)(Bsl + row * 32 + ((g ^ ((row >> 1) & 3)) << 3));
    }
    if (kt < 22) stageA_write(kt + 2);
    if (kt < 21) stageA_load(kt + 3);
    __builtin_amdgcn_s_barrier();
    asm volatile("s_waitcnt lgkmcnt(0)" ::: "memory");
    __builtin_amdgcn_sched_barrier(0);
    __builtin_amdgcn_s_setprio(1);
    #pragma unroll
    for (int i = 0; i < 4; ++i)
      #pragma unroll
      for (int ns = 0; ns < 4; ++ns)
        acc[i][ns] = mfma16(af[i], bfr[ns], acc[i][ns]);
    __builtin_amdgcn_s_setprio(0);
    __builtin_amdgcn_s_barrier();

    // ---- phase B (M-frags 4..7): 4 ds_read + stage B(kt+3)
    #pragma unroll
    for (int i = 0; i < 4; ++i){
      int row = wm * 128 + (4 + i) * 16 + c;
      af[i] = *(const bf16x8*)(Asl + row * 32 + ((g ^ ((row >> 1) & 3)) << 3));
    }
    if (kt < 21) stageB(kt + 3);
    __builtin_amdgcn_s_barrier();
    asm volatile("s_waitcnt lgkmcnt(0)" ::: "memory");
    __builtin_amdgcn_sched_barrier(0);
    __builtin_amdgcn_s_setprio(1);
    #pragma unroll
    for (int i = 0; i < 4; ++i)
      #pragma unroll
      for (int ns = 0; ns < 4; ++ns)
        acc[4 + i][ns] = mfma16(af[i], bfr[ns], acc[4 + i][ns]);
    __builtin_amdgcn_s_setprio(0);
    // drain exactly B(kt+1) (oldest 2 of 10 outstanding); tail 2/0
    if (kt <= 20)      asm volatile("s_waitcnt vmcnt(8)" ::: "memory");
    else if (kt == 21) asm volatile("s_waitcnt vmcnt(2)" ::: "memory");
    else if (kt == 22) asm volatile("s_waitcnt vmcnt(0)" ::: "memory");
    __builtin_amdgcn_s_barrier();
  }

  // ---- epilogue: wave-private 8KB LDS chunk -> coalesced 16B stores
  int n0g = n0 + wn * 64;                    // 64 cols = exactly one head
  const float* bias = (mat == 0) ? bq : (mat == 1 ? bk : bv);
  float bb[4];
  #pragma unroll
  for (int ns = 0; ns < 4; ++ns) bb[ns] = bias[n0g + ns * 16 + c];
  short* chunk = smem + wv * 4096;           // 8 KB per wave
  int hq = n0g >> 6;

  if (mat < 2){
    short* O = (mat == 0) ? Qw : Kw;
    float scl = (mat == 0) ? QSCALE : 1.0f;
    #pragma unroll
    for (int sp = 0; sp < 2; ++sp){
      #pragma unroll
      for (int msl = 0; msl < 4; ++msl){
        #pragma unroll
        for (int ns = 0; ns < 4; ++ns){
          int col = ns * 16 + c;             // hs
          #pragma unroll
          for (int i = 0; i < 4; ++i){
            int row = msl * 16 + g * 4 + i;  // s-local 0..63
            chunk[row * 64 + (((col >> 3) ^ (row & 7)) << 3) + (col & 7)] =
                (short)f2bf((acc[sp * 4 + msl][ns][i] + bb[ns]) * scl);
          }
        }
      }
      asm volatile("s_waitcnt lgkmcnt(0)" ::: "memory");
      __builtin_amdgcn_sched_barrier(0);
      #pragma unroll
      for (int rr = 0; rr < 8; ++rr){
        int row = rr * 8 + (l >> 3);         // 0..63, all 64 rows covered
        int slot = l & 7;
        bf16x8 v = *(const bf16x8*)(chunk + row * 64 + ((slot ^ (row & 7)) << 3));
        int m = m0 + wm * 128 + sp * 64 + row;
        int b = m >> 9, s2 = m & 511;
        *(bf16x8*)(O + (((long)(b * NH + hq) * NS + s2) << 6) + slot * 8) = v;
      }
      if (sp == 0){ asm volatile("s_waitcnt lgkmcnt(0)" ::: "memory"); }
    }
  } else {
    #pragma unroll
    for (int sp = 0; sp < 2; ++sp){
      #pragma unroll
      for (int msl = 0; msl < 4; ++msl){
        #pragma unroll
        for (int ns = 0; ns < 4; ++ns){
          int hs = ns * 16 + c;              // row 0..63
          #pragma unroll
          for (int i = 0; i < 4; ++i){
            int col = msl * 16 + g * 4 + i;  // s-local 0..63
            chunk[hs * 64 + (((col >> 3) ^ (hs & 7)) << 3) + (col & 7)] =
                (short)f2bf(acc[sp * 4 + msl][ns][i] + bb[ns]);
          }
        }
      }
      asm volatile("s_waitcnt lgkmcnt(0)" ::: "memory");
      __builtin_amdgcn_sched_barrier(0);
      int mbase = m0 + wm * 128 + sp * 64;   // 64-aligned, never crosses b
      int b = mbase >> 9, s0 = mbase & 511;
      #pragma unroll
      for (int rr = 0; rr < 8; ++rr){
        int hs = rr * 8 + (l >> 3);
        int slot = l & 7;
        bf16x8 v = *(const bf16x8*)(chunk + hs * 64 + ((slot ^ (hs & 7)) << 3));
        *(bf16x8*)(Vtw + (long)((b * NH + hq) * 64 + hs) * NS + s0 + slot * 8) = v;
      }
      if (sp == 0){ asm volatile("s_waitcnt lgkmcnt(0)" ::: "memory"); }
    }
  }
}

// ---------------- attention v3: 32x32 MFMA, swapped operands, P in registers.
// One (b,h) per block, 8 waves; each wave: 2 tiles of 32 q-rows, online softmax
// over 16 chunks of 32 keys. (unchanged — passing) --------
__global__ __launch_bounds__(512, 1)
void attn_kernel(const short* __restrict__ Qw, const short* __restrict__ Kw,
                 const short* __restrict__ Vtw, float* __restrict__ out){
  extern __shared__ char smem[];
  short* Ks = (short*)smem;              // [512][64] bf16, swizzled rows 128B, 64 KB
  short* Vs = (short*)(smem + 65536);    // [64][512] bf16, swizzled rows 1KB, 64 KB

  int bh = blockIdx.x;                   // 768 blocks
  int t = threadIdx.x, wv = t >> 6, l = t & 63;
  int lam = l & 31, hi = l >> 5;
  int r7 = lam & 7;

  const short* Kb = Kw  + (long)bh * NS * NHS;
  const short* Vb = Vtw + (long)bh * NS * NHS;

  // stage K [key][d] and Vt [d][key] once, 128 chunks of 1KB over 8 waves
  #pragma unroll
  for (int it = 0; it < 8; ++it){
    int chunk = it * 8 + wv;             // wave-uniform, 0..63
    {
      int idx = chunk * 64 + l;
      int row = idx >> 3, slot = idx & 7;
      const short* gk = Kb + row * 64 + ((slot ^ (row & 7)) * 8);
      __builtin_amdgcn_global_load_lds((const GAS unsigned int*)gk,
                                       (LAS unsigned int*)(Ks + chunk * 512), 16, 0, 0);
    }
    {
      int row = chunk, slot = l;         // one chunk = one d-row
      const short* gv = Vb + (long)row * NS + (((slot & 56) | ((slot & 7) ^ (row & 7))) * 8);
      __builtin_amdgcn_global_load_lds((const GAS unsigned int*)gv,
                                       (LAS unsigned int*)(Vs + chunk * 512), 16, 0, 0);
    }
  }
  __syncthreads();

  int b = bh / NH, h = bh - b * NH;
  float* outb = out + (long)b * NS * ND + (long)h * 64;

  for (int qt = 0; qt < 2; ++qt){
    int q0 = wv * 64 + qt * 32;
    // Q as B-operand: B[k=hi*8+j][col=q=lam], d = dk*16 + hi*8 + j
    const short* Qb = Qw + (((long)bh * NS + q0 + lam) << 6) + hi * 8;
    bf16x8 qf[4];
    #pragma unroll
    for (int dk = 0; dk < 4; ++dk) qf[dk] = *(const bf16x8*)(Qb + dk * 16);

    f32x16 o0, o1;                       // O[q=q0+lam][d=(reg&3)+8*(reg>>2)+4*hi+32*dh]
    #pragma unroll
    for (int j = 0; j < 16; ++j){ o0[j] = 0.f; o1[j] = 0.f; }
    float m_run = -1e30f, lsum = 0.f;

    #pragma unroll
    for (int ch = 0; ch < 16; ++ch){
      // ---- QK^T (swapped): s[reg] = S[key=ch*32+(reg&3)+8*(reg>>2)+4*hi][q=q0+lam]
      f32x16 s;
      #pragma unroll
      for (int j = 0; j < 16; ++j) s[j] = 0.f;
      const char* kbase = (const char*)Ks + (ch * 32 + lam) * 128;
      #pragma unroll
      for (int dk = 0; dk < 4; ++dk){
        bf16x8 kf = *(const bf16x8*)(kbase + (((hi + 2 * dk) ^ r7) << 4));
        s = mfma32(kf, qf[dk], s);
      }

      // ---- online softmax (defer-max, THR=8), per-lane q = lam
      float t8[8], t4[4];
      #pragma unroll
      for (int j = 0; j < 8; ++j) t8[j] = fmaxf(s[j], s[j + 8]);
      #pragma unroll
      for (int j = 0; j < 4; ++j) t4[j] = fmaxf(t8[j], t8[j + 4]);
      float m1 = fmaxf(fmaxf(t4[0], t4[1]), fmaxf(t4[2], t4[3]));
      float pmax = fmaxf(m1, __shfl_xor(m1, 32));
      if (__any(pmax > m_run + 8.0f)){
        float mnew = fmaxf(m_run, pmax);
        float cf = exp2f(m_run - mnew);
        lsum *= cf;
        #pragma unroll
        for (int j = 0; j < 16; ++j){ o0[j] *= cf; o1[j] *= cf; }
        m_run = mnew;
      }
      float p[16];
      #pragma unroll
      for (int j = 0; j < 16; ++j) p[j] = exp2f(s[j] - m_run);
      float a8[8], a4[4];
      #pragma unroll
      for (int j = 0; j < 8; ++j) a8[j] = p[j] + p[j + 8];
      #pragma unroll
      for (int j = 0; j < 4; ++j) a4[j] = a8[j] + a8[j + 4];
      lsum += (a4[0] + a4[1]) + (a4[2] + a4[3]);

      // ---- P -> bf16 fragments, single-partner exchange (lane ^ 32)
      unsigned int w[8];
      #pragma unroll
      for (int rr = 0; rr < 8; ++rr) w[rr] = cvtpk(p[2 * rr], p[2 * rr + 1]);
      unsigned int y0 = (unsigned int)__shfl_xor((int)(hi ? w[0] : w[2]), 32);
      unsigned int y1 = (unsigned int)__shfl_xor((int)(hi ? w[1] : w[3]), 32);
      unsigned int y2 = (unsigned int)__shfl_xor((int)(hi ? w[4] : w[6]), 32);
      unsigned int y3 = (unsigned int)__shfl_xor((int)(hi ? w[5] : w[7]), 32);
      u32x4 fa, fb;
      if (hi){
        fa[0] = y0;   fa[1] = y1;   fa[2] = w[2]; fa[3] = w[3];   // keys 8..15
        fb[0] = y2;   fb[1] = y3;   fb[2] = w[6]; fb[3] = w[7];   // keys 24..31
      } else {
        fa[0] = w[0]; fa[1] = w[1]; fa[2] = y0;   fa[3] = y1;     // keys 0..7
        fb[0] = w[4]; fb[1] = w[5]; fb[2] = y2;   fb[3] = y3;     // keys 16..23
      }
      bf16x8 pa = u2b(fa), pb = u2b(fb);

      // ---- PV (swapped): o[dh] += mfma32(V^T-frag, P-frag)
      const char* vb0 = (const char*)Vs + lam * 1024;          // d = lam
      const char* vb1 = (const char*)Vs + (32 + lam) * 1024;   // d = 32+lam
      int sl0 = ch * 4 + hi, sl1 = ch * 4 + 2 + hi;
      int sw0 = ((sl0 & 56) | ((sl0 & 7) ^ r7)) << 4;
      int sw1 = ((sl1 & 56) | ((sl1 & 7) ^ r7)) << 4;
      bf16x8 v00 = *(const bf16x8*)(vb0 + sw0);
      bf16x8 v01 = *(const bf16x8*)(vb0 + sw1);
      bf16x8 v10 = *(const bf16x8*)(vb1 + sw0);
      bf16x8 v11 = *(const bf16x8*)(vb1 + sw1);
      o0 = mfma32(v00, pa, o0);
      o0 = mfma32(v01, pb, o0);
      o1 = mfma32(v10, pa, o1);
      o1 = mfma32(v11, pb, o1);
    }

    // ---- epilogue: combine l across partner, deferred 1/sum, float4 stores
    float lt = lsum + __shfl_xor(lsum, 32);
    float invl = 1.0f / lt;
    float* orow = outb + (long)(q0 + lam) * ND;
    #pragma unroll
    for (int r = 0; r < 4; ++r){
      f4 u0, u1;
      #pragma unroll
      for (int jj = 0; jj < 4; ++jj){
        u0[jj] = o0[4 * r + jj] * invl;
        u1[jj] = o1[4 * r + jj] * invl;
      }
      *(f4*)(orow + 4 * hi + 8 * r)      = u0;   // d = 4hi+8r+{0..3}
      *(f4*)(orow + 32 + 4 * hi + 8 * r) = u1;   // d = 32+4hi+8r+{0..3}
    }
  }
}

// ---------------- launch ----------------
extern "C" void kernel_launch(void* const* d_in, const int* in_sizes, int n_in,
                              void* d_out, int out_size, void* d_ws, size_t ws_size,
                              hipStream_t stream){
  const float* from_t = (const float*)d_in[0];
  const float* to_t   = (const float*)d_in[1];
  const float* Wq = (const float*)d_in[2];
  const float* bq = (const float*)d_in[3];
  const float* Wk = (const float*)d_in[4];
  const float* bk = (const float*)d_in[5];
  const float* Wv = (const float*)d_in[6];
  const float* bv = (const float*)d_in[7];

  short* Wt  = (short*)d_ws;                 // 1769472 bf16
  short* Qw  = Wt  + 1769472;                // 25165824
  short* Kw  = Qw  + 25165824;               // 25165824
  short* Vtw = Kw  + 25165824;               // 25165824  (total ~147 MB)

  cvt_w<<<6912, 256, 0, stream>>>(Wq, Wk, Wv, Wt);
  qkv_gemm<<<1152, 512, 0, stream>>>(from_t, to_t, Wt, bq, bk, bv, Qw, Kw, Vtw);
  attn_kernel<<<768, 512, 131072, stream>>>(Qw, Kw, Vtw, (float*)d_out);
}